// Round 5
// baseline (563.233 us; speedup 1.0000x reference)
//
#include <hip/hip_runtime.h>
#include <math.h>

// Problem constants (fixed by setup_inputs)
constexpr int B_   = 2;
constexpr int C_   = 64;
constexpr int H_   = 128;
constexpr int W_   = 128;
constexpr int HW_  = H_ * W_;
constexpr int DG_  = 16;   // deformable groups
constexpr int KK_  = 9;    // 3x3 taps
constexpr int CG_  = 4;    // channels per group = C/DG
constexpr int OFFC_ = 3 * KK_ * DG_;  // 432
constexpr int R_   = C_ * KK_;        // 576 reduction length of final einsum
constexpr int RS_  = 4;               // einsum r-slices
constexpr int RL_  = R_ / RS_;        // 144 per slice

// ---------------------------------------------------------------------------
// Weight transpose: in[OC][IC9] -> out[IC9][OC]  (OC contiguous -> one
// s_load_dwordx16 per 16-chan chunk instead of 16 strided s_load_dword).
// ---------------------------------------------------------------------------
template <int OC, int IC9>
__global__ __launch_bounds__(256) void transpose_w_k(
    const float* __restrict__ in, float* __restrict__ out)
{
    const int j = blockIdx.x * 256 + threadIdx.x;
    if (j >= OC * IC9) return;
    const int row = j / OC;   // ic*9 + tap
    const int col = j - row * OC;
    out[j] = in[(size_t)col * IC9 + row];
}

// ---------------------------------------------------------------------------
// Direct 3x3 conv, pad=1. Thread: PX pixels x 16 out chans.
// ---------------------------------------------------------------------------
template <int CIN, int COUT, int PX>
__global__ __launch_bounds__(256) void conv3x3_leaky_k(
    const float* __restrict__ in, const float* __restrict__ wt,
    const float* __restrict__ bias, float* __restrict__ out)
{
    const int xp = blockIdx.x * 16 + threadIdx.x;
    const int yb = (blockIdx.y * 16 + threadIdx.y) * PX;
    const int z  = blockIdx.z;
    constexpr int NCHUNK = COUT / 16;
    const int b   = z / NCHUNK;
    const int ocb = (z % NCHUNK) * 16;

    float acc[PX][16];
#pragma unroll
    for (int p = 0; p < PX; ++p)
#pragma unroll
        for (int o = 0; o < 16; ++o) acc[p][o] = bias[ocb + o];

    const bool vxm = (xp - 1 >= 0);
    const bool vxp = (xp + 1 < W_);
    bool vr[PX + 2];
#pragma unroll
    for (int r = 0; r < PX + 2; ++r)
        vr[r] = ((unsigned)(yb + r - 1) < (unsigned)H_);

    const float* inb = in + (size_t)b * CIN * HW_;
    for (int ic = 0; ic < CIN; ++ic) {
        const float* inc = inb + (size_t)ic * HW_;
        float rv[PX + 2][3];
#pragma unroll
        for (int r = 0; r < PX + 2; ++r) {
            const int yy = yb + r - 1;
            const float* rowp = inc + yy * W_ + xp;
            rv[r][0] = (vr[r] && vxm) ? rowp[-1] : 0.f;
            rv[r][1] = vr[r] ? rowp[0] : 0.f;
            rv[r][2] = (vr[r] && vxp) ? rowp[1] : 0.f;
        }
        const float* wrow = wt + (size_t)(ic * 9) * COUT + ocb;
#pragma unroll
        for (int t = 0; t < 9; ++t) {
            float wv[16];
#pragma unroll
            for (int o = 0; o < 16; ++o) wv[o] = wrow[(size_t)t * COUT + o];
#pragma unroll
            for (int p = 0; p < PX; ++p) {
                const float v = rv[p + t / 3][t % 3];
#pragma unroll
                for (int o = 0; o < 16; ++o)
                    acc[p][o] = fmaf(v, wv[o], acc[p][o]);
            }
        }
    }

#pragma unroll
    for (int p = 0; p < PX; ++p) {
        const int pix = (yb + p) * W_ + xp;
#pragma unroll
        for (int o = 0; o < 16; ++o) {
            float r = acc[p][o];
            r = (r >= 0.f) ? r : 0.1f * r;
            out[((size_t)(b * COUT + ocb + o)) * HW_ + pix] = r;
        }
    }
}

// ---------------------------------------------------------------------------
// Conv3 (64 -> 432) with fused offset/mask epilogue, PX pixels/thread.
// PX=4: 576 FMA per 18 input loads per ic -> high FMA density + deep ILP.
// omap[b][g*9+k][slot][H][W], slot 0=off_y 1=off_x 2=mask.
// ---------------------------------------------------------------------------
template <int PX>
__global__ __launch_bounds__(256) void conv3_off_k(
    const float* __restrict__ in, const float* __restrict__ wt,
    const float* __restrict__ bias, const float* __restrict__ flow,
    float* __restrict__ omap)
{
    const int xp = blockIdx.x * 16 + threadIdx.x;
    const int yb = (blockIdx.y * 16 + threadIdx.y) * PX;
    const int z  = blockIdx.z;
    constexpr int CIN = 64;
    constexpr int COUT = OFFC_;
    constexpr int NCHUNK = COUT / 16;   // 27
    const int b   = z / NCHUNK;
    const int ocb = (z % NCHUNK) * 16;

    float acc[PX][16];
#pragma unroll
    for (int p = 0; p < PX; ++p)
#pragma unroll
        for (int o = 0; o < 16; ++o) acc[p][o] = bias[ocb + o];

    const bool vxm = (xp - 1 >= 0);
    const bool vxp = (xp + 1 < W_);
    bool vr[PX + 2];
#pragma unroll
    for (int r = 0; r < PX + 2; ++r)
        vr[r] = ((unsigned)(yb + r - 1) < (unsigned)H_);

    const float* inb = in + (size_t)b * CIN * HW_;
    for (int ic = 0; ic < CIN; ++ic) {
        const float* inc = inb + (size_t)ic * HW_;
        float rv[PX + 2][3];
#pragma unroll
        for (int r = 0; r < PX + 2; ++r) {
            const int yy = yb + r - 1;
            const float* rowp = inc + yy * W_ + xp;
            rv[r][0] = (vr[r] && vxm) ? rowp[-1] : 0.f;
            rv[r][1] = vr[r] ? rowp[0] : 0.f;
            rv[r][2] = (vr[r] && vxp) ? rowp[1] : 0.f;
        }
        const float* wrow = wt + (size_t)(ic * 9) * COUT + ocb;
#pragma unroll
        for (int t = 0; t < 9; ++t) {
            float wv[16];
#pragma unroll
            for (int o = 0; o < 16; ++o) wv[o] = wrow[(size_t)t * COUT + o];
#pragma unroll
            for (int p = 0; p < PX; ++p) {
                const float v = rv[p + t / 3][t % 3];
#pragma unroll
                for (int o = 0; o < 16; ++o)
                    acc[p][o] = fmaf(v, wv[o], acc[p][o]);
            }
        }
    }

#pragma unroll
    for (int p = 0; p < PX; ++p) {
        const int pix = (yb + p) * W_ + xp;
#pragma unroll
        for (int o = 0; o < 16; ++o) {
            const int oc = ocb + o;
            float val = acc[p][o];
            int g, k, slot;
            if (oc < 2 * DG_ * KK_) {          // offset channels (0..287)
                g = oc / 18;
                const int rem = oc - g * 18;
                k = rem >> 1;
                slot = rem & 1;                 // 0 = y, 1 = x
                const float fl = flow[(size_t)(b * 2 + (1 - slot)) * HW_ + pix];
                val = 10.f * tanhf(val) + fl;
            } else {                            // mask channels (288..431)
                const int c = oc - 2 * DG_ * KK_;
                g = c / 9;
                k = c - g * 9;
                slot = 2;
                val = 1.f / (1.f + expf(-val));
            }
            omap[((size_t)((b * DG_ * KK_ + g * KK_ + k) * 3 + slot)) * HW_ + pix] = val;
        }
    }
}

// ---------------------------------------------------------------------------
// Phase A: bilinear gather. Thread = (pixel, one (g,k) tap). Tiny VGPR state,
// 18432 blocks -> full occupancy; every gather computed exactly once.
// val[b][(g*4+c)*9 + k][pix] = masked bilinear sample.
// ---------------------------------------------------------------------------
__global__ __launch_bounds__(256) void gather_k(
    const float* __restrict__ x, const float* __restrict__ omap,
    float* __restrict__ val)
{
    const int pix = blockIdx.x * 256 + threadIdx.x;
    const int z   = blockIdx.y;               // b * 144 + g*9 + k
    const int b   = z / (DG_ * KK_);
    const int gk  = z - b * DG_ * KK_;
    const int g   = gk / KK_;
    const int k   = gk - g * KK_;
    const int yp  = pix >> 7;
    const int xp  = pix & (W_ - 1);

    const size_t obase = ((size_t)(b * DG_ * KK_ + gk) * 3) * HW_ + pix;
    const float oy = omap[obase];
    const float ox = omap[obase + HW_];
    const float m  = omap[obase + 2 * HW_];

    const float py = (float)(yp + (k / 3) - 1) + oy;
    const float px = (float)(xp + (k % 3) - 1) + ox;
    const float y0f = floorf(py);
    const float x0f = floorf(px);
    const float wy = py - y0f;
    const float wx = px - x0f;
    const int y0 = (int)y0f, x0 = (int)x0f;
    const int y1 = y0 + 1,  x1 = x0 + 1;
    const bool vy0 = ((unsigned)y0 < (unsigned)H_);
    const bool vy1 = ((unsigned)y1 < (unsigned)H_);
    const bool vx0 = ((unsigned)x0 < (unsigned)W_);
    const bool vx1 = ((unsigned)x1 < (unsigned)W_);
    const float w00 = vy0 && vx0 ? (1.f - wy) * (1.f - wx) : 0.f;
    const float w01 = vy0 && vx1 ? (1.f - wy) * wx         : 0.f;
    const float w10 = vy1 && vx0 ? wy * (1.f - wx)         : 0.f;
    const float w11 = vy1 && vx1 ? wy * wx                 : 0.f;
    const int i00 = (vy0 && vx0) ? y0 * W_ + x0 : 0;
    const int i01 = (vy0 && vx1) ? y0 * W_ + x1 : 0;
    const int i10 = (vy1 && vx0) ? y1 * W_ + x0 : 0;
    const int i11 = (vy1 && vx1) ? y1 * W_ + x1 : 0;

    const float* xg = x + (size_t)(b * C_ + g * CG_) * HW_;
    float* vg = val + ((size_t)b * R_ + (size_t)(g * CG_) * KK_ + k) * HW_ + pix;
#pragma unroll
    for (int c = 0; c < CG_; ++c) {
        const float* img = xg + (size_t)c * HW_;
        float v = w00 * img[i00] + w01 * img[i01] + w10 * img[i10] + w11 * img[i11];
        vg[(size_t)c * KK_ * HW_] = v * m;
    }
}

// ---------------------------------------------------------------------------
// Phase B1: partial einsum over an r-slice of 144.
// part[slice][b][o][pix] = sum_{r in slice} val[b][r][pix] * wkT[r][o].
// 2048 blocks -> 32 waves/CU (vs 8 for the monolithic version).
// ---------------------------------------------------------------------------
__global__ __launch_bounds__(256) void einsum_part_k(
    const float* __restrict__ val, const float* __restrict__ wkT,
    float* __restrict__ part)
{
    const int pix = blockIdx.x * 256 + threadIdx.x;
    const int z   = blockIdx.y;               // b(2) x ocb(4) x slice(4)
    const int b   = z >> 4;
    const int ocb = ((z >> 2) & 3) * 16;
    const int sl  = z & 3;
    const int r0  = sl * RL_;

    float acc[16];
#pragma unroll
    for (int o = 0; o < 16; ++o) acc[o] = 0.f;

    const float* vb = val + ((size_t)b * R_ + r0) * HW_ + pix;
    const float* wp = wkT + (size_t)r0 * C_ + ocb;
#pragma unroll 4
    for (int r = 0; r < RL_; ++r) {
        const float s = vb[(size_t)r * HW_];
        const float* w = wp + (size_t)r * C_;
#pragma unroll
        for (int o = 0; o < 16; ++o)
            acc[o] = fmaf(s, w[o], acc[o]);
    }

    float* pb = part + (((size_t)(sl * B_ + b)) * C_ + ocb) * HW_ + pix;
#pragma unroll
    for (int o = 0; o < 16; ++o)
        pb[(size_t)o * HW_] = acc[o];
}

// ---------------------------------------------------------------------------
// Phase B2: combine the 4 r-slice partials into d_out (float4 vectorized).
// ---------------------------------------------------------------------------
__global__ __launch_bounds__(256) void combine_k(
    const float4* __restrict__ part, float4* __restrict__ out)
{
    constexpr int N4 = B_ * C_ * HW_ / 4;   // 524288
    const int i = blockIdx.x * 256 + threadIdx.x;
    if (i >= N4) return;
    float4 a = part[i];
    const float4 b = part[i + N4];
    const float4 c = part[i + 2 * N4];
    const float4 d = part[i + 3 * N4];
    a.x += b.x + c.x + d.x;
    a.y += b.y + c.y + d.y;
    a.z += b.z + c.z + d.z;
    a.w += b.w + c.w + d.w;
    out[i] = a;
}

// ---------------------------------------------------------------------------
extern "C" void kernel_launch(void* const* d_in, const int* in_sizes, int n_in,
                              void* d_out, int out_size, void* d_ws, size_t ws_size,
                              hipStream_t stream)
{
    const float* x    = (const float*)d_in[0];
    const float* ef   = (const float*)d_in[1];
    const float* flow = (const float*)d_in[2];
    const float* w1   = (const float*)d_in[3];
    const float* b1   = (const float*)d_in[4];
    const float* w2   = (const float*)d_in[5];
    const float* b2   = (const float*)d_in[6];
    const float* w3   = (const float*)d_in[7];
    const float* b3   = (const float*)d_in[8];
    const float* wk   = (const float*)d_in[9];
    float* out = (float*)d_out;

    // Workspace layout (floats):
    //   h1:  B*64*HW    = 2,097,152   (8.4 MB)
    //   h2:  B*64*HW    = 2,097,152   (8.4 MB)
    //   om:  B*432*HW   = 14,155,776  (56.6 MB)  -- dead after gather_k;
    //        einsum partials (4*B*64*HW = 8,388,608 fl = 33.6 MB) alias it.
    //   val: B*576*HW   = 18,874,368  (75.5 MB)
    //   wt*:            ~ 0.4M        total ~150 MB
    float* h1  = (float*)d_ws;
    float* h2  = h1 + (size_t)B_ * C_ * HW_;
    float* om  = h2 + (size_t)B_ * C_ * HW_;
    float* val = om + (size_t)B_ * OFFC_ * HW_;
    float* wt1 = val + (size_t)B_ * R_ * HW_;
    float* wt2 = wt1 + 1152 * 64;
    float* wt3 = wt2 + 576 * 64;
    float* wkT = wt3 + 576 * 432;
    float* part = om;   // alias: om is consumed by gather_k before einsum runs

    transpose_w_k<64, 1152><<<dim3((64 * 1152 + 255) / 256), 256, 0, stream>>>(w1, wt1);
    transpose_w_k<64, 576><<<dim3((64 * 576 + 255) / 256), 256, 0, stream>>>(w2, wt2);
    transpose_w_k<432, 576><<<dim3((432 * 576 + 255) / 256), 256, 0, stream>>>(w3, wt3);
    transpose_w_k<64, 576><<<dim3((64 * 576 + 255) / 256), 256, 0, stream>>>(wk, wkT);

    dim3 blk(16, 16, 1);
    conv3x3_leaky_k<2 * C_, C_, 1><<<dim3(W_ / 16, H_ / 16, B_ * (C_ / 16)), blk, 0, stream>>>(ef, wt1, b1, h1);
    conv3x3_leaky_k<C_, C_, 1><<<dim3(W_ / 16, H_ / 16, B_ * (C_ / 16)), blk, 0, stream>>>(h1, wt2, b2, h2);
    conv3_off_k<4><<<dim3(W_ / 16, H_ / 64, B_ * (OFFC_ / 16)), blk, 0, stream>>>(h2, wt3, b3, flow, om);

    gather_k<<<dim3(HW_ / 256, B_ * DG_ * KK_), 256, 0, stream>>>(x, om, val);
    einsum_part_k<<<dim3(HW_ / 256, B_ * 4 * RS_), 256, 0, stream>>>(val, wkT, part);
    combine_k<<<dim3((B_ * C_ * HW_ / 4 + 255) / 256), 256, 0, stream>>>((const float4*)part, (float4*)out);
}

// Round 7
// 519.461 us; speedup vs baseline: 1.0843x; 1.0843x over previous
//
#include <hip/hip_runtime.h>
#include <math.h>

// Problem constants (fixed by setup_inputs)
constexpr int B_   = 2;
constexpr int C_   = 64;
constexpr int H_   = 128;
constexpr int W_   = 128;
constexpr int HW_  = H_ * W_;
constexpr int DG_  = 16;   // deformable groups
constexpr int KK_  = 9;    // 3x3 taps
constexpr int CG_  = 4;    // channels per group = C/DG
constexpr int OFFC_ = 3 * KK_ * DG_;  // 432
constexpr int R_   = C_ * KK_;        // 576 reduction length (tap-major K)
constexpr int RS_  = 4;               // einsum r-slices
constexpr int RL_  = R_ / RS_;        // 144 per slice

typedef _Float16 half8 __attribute__((ext_vector_type(8)));  // 8 f16 = 4 VGPR
typedef float floatx4 __attribute__((ext_vector_type(4)));   // MFMA acc

// ---------------------------------------------------------------------------
// Weight transpose: in[OC][IC9] -> out[IC9][OC]  (OC contiguous -> one
// s_load_dwordx16 per 16-chan chunk instead of 16 strided s_load_dword).
// ---------------------------------------------------------------------------
template <int OC, int IC9>
__global__ __launch_bounds__(256) void transpose_w_k(
    const float* __restrict__ in, float* __restrict__ out)
{
    const int j = blockIdx.x * 256 + threadIdx.x;
    if (j >= OC * IC9) return;
    const int row = j / OC;   // ic*9 + tap
    const int col = j - row * OC;
    out[j] = in[(size_t)col * IC9 + row];
}

// ---------------------------------------------------------------------------
// w3 prep for MFMA: w3h[oc][t*64+ic] = f16(w3[oc][ic*9+t]).  (tap-major K)
// ---------------------------------------------------------------------------
__global__ __launch_bounds__(256) void prep_w3h_k(
    const float* __restrict__ w3, _Float16* __restrict__ w3h)
{
    const int j = blockIdx.x * 256 + threadIdx.x;   // oc*576 + t*64 + ic
    if (j >= OFFC_ * R_) return;
    const int oc  = j / R_;
    const int rem = j - oc * R_;
    const int t   = rem >> 6;
    const int ic  = rem & 63;
    w3h[j] = (_Float16)w3[(size_t)oc * R_ + ic * 9 + t];
}

// ---------------------------------------------------------------------------
// Direct 3x3 conv, pad=1. Thread: PX pixels x 16 out chans.
// ---------------------------------------------------------------------------
template <int CIN, int COUT, int PX>
__global__ __launch_bounds__(256) void conv3x3_leaky_k(
    const float* __restrict__ in, const float* __restrict__ wt,
    const float* __restrict__ bias, float* __restrict__ out)
{
    const int xp = blockIdx.x * 16 + threadIdx.x;
    const int yb = (blockIdx.y * 16 + threadIdx.y) * PX;
    const int z  = blockIdx.z;
    constexpr int NCHUNK = COUT / 16;
    const int b   = z / NCHUNK;
    const int ocb = (z % NCHUNK) * 16;

    float acc[PX][16];
#pragma unroll
    for (int p = 0; p < PX; ++p)
#pragma unroll
        for (int o = 0; o < 16; ++o) acc[p][o] = bias[ocb + o];

    const bool vxm = (xp - 1 >= 0);
    const bool vxp = (xp + 1 < W_);
    bool vr[PX + 2];
#pragma unroll
    for (int r = 0; r < PX + 2; ++r)
        vr[r] = ((unsigned)(yb + r - 1) < (unsigned)H_);

    const float* inb = in + (size_t)b * CIN * HW_;
    for (int ic = 0; ic < CIN; ++ic) {
        const float* inc = inb + (size_t)ic * HW_;
        float rv[PX + 2][3];
#pragma unroll
        for (int r = 0; r < PX + 2; ++r) {
            const int yy = yb + r - 1;
            const float* rowp = inc + yy * W_ + xp;
            rv[r][0] = (vr[r] && vxm) ? rowp[-1] : 0.f;
            rv[r][1] = vr[r] ? rowp[0] : 0.f;
            rv[r][2] = (vr[r] && vxp) ? rowp[1] : 0.f;
        }
        const float* wrow = wt + (size_t)(ic * 9) * COUT + ocb;
#pragma unroll
        for (int t = 0; t < 9; ++t) {
            float wv[16];
#pragma unroll
            for (int o = 0; o < 16; ++o) wv[o] = wrow[(size_t)t * COUT + o];
#pragma unroll
            for (int p = 0; p < PX; ++p) {
                const float v = rv[p + t / 3][t % 3];
#pragma unroll
                for (int o = 0; o < 16; ++o)
                    acc[p][o] = fmaf(v, wv[o], acc[p][o]);
            }
        }
    }

#pragma unroll
    for (int p = 0; p < PX; ++p) {
        const int pix = (yb + p) * W_ + xp;
#pragma unroll
        for (int o = 0; o < 16; ++o) {
            float r = acc[p][o];
            r = (r >= 0.f) ? r : 0.1f * r;
            out[((size_t)(b * COUT + ocb + o)) * HW_ + pix] = r;
        }
    }
}

// ---------------------------------------------------------------------------
// Conv3 via f16 MFMA implicit GEMM — RACE-FREE BY CONSTRUCTION:
//   * LDS (X strip) is written ONCE, then one __syncthreads(), then
//     read-only for the rest of the kernel. No WAR hazards possible.
//   * W fragments are loaded per-lane directly from global (L2-resident
//     0.5 MB), so no W staging and no further barriers.
// GEMM: D[oc][pix] = sum_k W[oc][k] * X[k][pix], k = t*64+ic (K=576).
// A = weights (m=lane&15 -> oc), B = pixels (n=lane&15 -> pixel) =>
// C/D col=lane&15=pixel => coalesced epilogue stores.
// Block: one image row (128 px) x 144 oc; 4 waves = 4 x 32px.
// LDS: Xl[390][72] f16 (3 rows x 130 px halo, 64 ics, pad 72) = 56.2 KB.
// Epilogue fuses bias + 10*tanh + flow add / sigmoid, writes omap.
// ---------------------------------------------------------------------------
__global__ __launch_bounds__(256) void conv3_mfma_k(
    const float* __restrict__ h2, const _Float16* __restrict__ w3h,
    const float* __restrict__ bias, const float* __restrict__ flow,
    float* __restrict__ omap)
{
    __shared__ __align__(16) _Float16 Xl[390 * 72];  // [dy*130+xi][ic]

    const int tid  = threadIdx.x;
    const int lane = tid & 63;
    const int wv   = tid >> 6;       // wave id 0..3
    const int l15  = lane & 15;
    const int quad = lane >> 4;

    const int row = blockIdx.x;      // b*128 + y
    const int b   = row >> 7;
    const int y   = row & 127;
    const int m0  = blockIdx.y * 144;  // oc tile base

    const float* h2b = h2 + (size_t)b * C_ * HW_;

    // ---- stage X once: 64 ics x (3 rows x 130 px halo), zero-padded ----
    for (int i = tid; i < 64 * 390; i += 256) {
        const int icl = i / 390;         // 0..63
        const int r   = i - icl * 390;   // dy*130 + xi
        const int dy  = r / 130;
        const int xi  = r - dy * 130;
        const int yy  = y + dy - 1;
        const int xx  = xi - 1;
        float v = 0.f;
        if ((unsigned)yy < (unsigned)H_ && (unsigned)xx < (unsigned)W_)
            v = h2b[(size_t)icl * HW_ + yy * W_ + xx];
        Xl[r * 72 + icl] = (_Float16)v;
    }
    __syncthreads();   // the ONLY barrier; LDS is read-only hereafter

    floatx4 acc[9][2];
#pragma unroll
    for (int mf = 0; mf < 9; ++mf)
#pragma unroll
        for (int nf = 0; nf < 2; ++nf)
            acc[mf][nf] = (floatx4){0.f, 0.f, 0.f, 0.f};

    for (int t = 0; t < 9; ++t) {
        const int dy = t / 3, dx = t % 3;
#pragma unroll
        for (int h = 0; h < 2; ++h) {        // two 32-ic halves of K
            half8 bfr[2];
#pragma unroll
            for (int nf = 0; nf < 2; ++nf) {
                const int px = wv * 32 + nf * 16 + l15;
                bfr[nf] = *(const half8*)&Xl[(dy * 130 + px + dx) * 72 + h * 32 + quad * 8];
            }
#pragma unroll
            for (int mf = 0; mf < 9; ++mf) {
                const half8 afr = *(const half8*)&w3h[
                    (size_t)(m0 + mf * 16 + l15) * R_ + t * 64 + h * 32 + quad * 8];
#pragma unroll
                for (int nf = 0; nf < 2; ++nf)
                    acc[mf][nf] = __builtin_amdgcn_mfma_f32_16x16x32_f16(
                        afr, bfr[nf], acc[mf][nf], 0, 0, 0);
            }
        }
    }

    // ---- epilogue: bias + offset/mask transform, coalesced omap stores ----
#pragma unroll
    for (int mf = 0; mf < 9; ++mf) {
#pragma unroll
        for (int nf = 0; nf < 2; ++nf) {
#pragma unroll
            for (int reg = 0; reg < 4; ++reg) {
                const int oc  = m0 + mf * 16 + quad * 4 + reg;
                const int px  = wv * 32 + nf * 16 + l15;
                const int pix = y * W_ + px;
                float val = acc[mf][nf][reg] + bias[oc];
                int g, k, slot;
                if (oc < 2 * DG_ * KK_) {          // offset channels
                    g = oc / 18;
                    const int rem = oc - g * 18;
                    k = rem >> 1;
                    slot = rem & 1;                 // 0 = y, 1 = x
                    const float fl = flow[(size_t)(b * 2 + (1 - slot)) * HW_ + pix];
                    val = 10.f * tanhf(val) + fl;
                } else {                            // mask channels
                    const int c = oc - 2 * DG_ * KK_;
                    g = c / 9;
                    k = c - g * 9;
                    slot = 2;
                    val = 1.f / (1.f + expf(-val));
                }
                omap[((size_t)((b * DG_ * KK_ + g * KK_ + k) * 3 + slot)) * HW_ + pix] = val;
            }
        }
    }
}

// ---------------------------------------------------------------------------
// Phase A: bilinear gather. Thread = (pixel, one (g,k) tap).
// val[b][(g*4+c)*9 + k][pix] = masked bilinear sample.
// ---------------------------------------------------------------------------
__global__ __launch_bounds__(256) void gather_k(
    const float* __restrict__ x, const float* __restrict__ omap,
    float* __restrict__ val)
{
    const int pix = blockIdx.x * 256 + threadIdx.x;
    const int z   = blockIdx.y;               // b * 144 + g*9 + k
    const int b   = z / (DG_ * KK_);
    const int gk  = z - b * DG_ * KK_;
    const int g   = gk / KK_;
    const int k   = gk - g * KK_;
    const int yp  = pix >> 7;
    const int xp  = pix & (W_ - 1);

    const size_t obase = ((size_t)(b * DG_ * KK_ + gk) * 3) * HW_ + pix;
    const float oy = omap[obase];
    const float ox = omap[obase + HW_];
    const float m  = omap[obase + 2 * HW_];

    const float py = (float)(yp + (k / 3) - 1) + oy;
    const float px = (float)(xp + (k % 3) - 1) + ox;
    const float y0f = floorf(py);
    const float x0f = floorf(px);
    const float wy = py - y0f;
    const float wx = px - x0f;
    const int y0 = (int)y0f, x0 = (int)x0f;
    const int y1 = y0 + 1,  x1 = x0 + 1;
    const bool vy0 = ((unsigned)y0 < (unsigned)H_);
    const bool vy1 = ((unsigned)y1 < (unsigned)H_);
    const bool vx0 = ((unsigned)x0 < (unsigned)W_);
    const bool vx1 = ((unsigned)x1 < (unsigned)W_);
    const float w00 = vy0 && vx0 ? (1.f - wy) * (1.f - wx) : 0.f;
    const float w01 = vy0 && vx1 ? (1.f - wy) * wx         : 0.f;
    const float w10 = vy1 && vx0 ? wy * (1.f - wx)         : 0.f;
    const float w11 = vy1 && vx1 ? wy * wx                 : 0.f;
    const int i00 = (vy0 && vx0) ? y0 * W_ + x0 : 0;
    const int i01 = (vy0 && vx1) ? y0 * W_ + x1 : 0;
    const int i10 = (vy1 && vx0) ? y1 * W_ + x0 : 0;
    const int i11 = (vy1 && vx1) ? y1 * W_ + x1 : 0;

    const float* xg = x + (size_t)(b * C_ + g * CG_) * HW_;
    float* vg = val + ((size_t)b * R_ + (size_t)(g * CG_) * KK_ + k) * HW_ + pix;
#pragma unroll
    for (int c = 0; c < CG_; ++c) {
        const float* img = xg + (size_t)c * HW_;
        float v = w00 * img[i00] + w01 * img[i01] + w10 * img[i10] + w11 * img[i11];
        vg[(size_t)c * KK_ * HW_] = v * m;
    }
}

// ---------------------------------------------------------------------------
// Phase B1: partial einsum over an r-slice of 144.
// part[slice][b][o][pix] = sum_{r in slice} val[b][r][pix] * wkT[r][o].
// ---------------------------------------------------------------------------
__global__ __launch_bounds__(256) void einsum_part_k(
    const float* __restrict__ val, const float* __restrict__ wkT,
    float* __restrict__ part)
{
    const int pix = blockIdx.x * 256 + threadIdx.x;
    const int z   = blockIdx.y;               // b(2) x ocb(4) x slice(4)
    const int b   = z >> 4;
    const int ocb = ((z >> 2) & 3) * 16;
    const int sl  = z & 3;
    const int r0  = sl * RL_;

    float acc[16];
#pragma unroll
    for (int o = 0; o < 16; ++o) acc[o] = 0.f;

    const float* vb = val + ((size_t)b * R_ + r0) * HW_ + pix;
    const float* wp = wkT + (size_t)r0 * C_ + ocb;
#pragma unroll 4
    for (int r = 0; r < RL_; ++r) {
        const float s = vb[(size_t)r * HW_];
        const float* w = wp + (size_t)r * C_;
#pragma unroll
        for (int o = 0; o < 16; ++o)
            acc[o] = fmaf(s, w[o], acc[o]);
    }

    float* pb = part + (((size_t)(sl * B_ + b)) * C_ + ocb) * HW_ + pix;
#pragma unroll
    for (int o = 0; o < 16; ++o)
        pb[(size_t)o * HW_] = acc[o];
}

// ---------------------------------------------------------------------------
// Phase B2: combine the 4 r-slice partials into d_out (float4 vectorized).
// ---------------------------------------------------------------------------
__global__ __launch_bounds__(256) void combine_k(
    const float4* __restrict__ part, float4* __restrict__ out)
{
    constexpr int N4 = B_ * C_ * HW_ / 4;   // 524288
    const int i = blockIdx.x * 256 + threadIdx.x;
    if (i >= N4) return;
    float4 a = part[i];
    const float4 b = part[i + N4];
    const float4 c = part[i + 2 * N4];
    const float4 d = part[i + 3 * N4];
    a.x += b.x + c.x + d.x;
    a.y += b.y + c.y + d.y;
    a.z += b.z + c.z + d.z;
    a.w += b.w + c.w + d.w;
    out[i] = a;
}

// ---------------------------------------------------------------------------
extern "C" void kernel_launch(void* const* d_in, const int* in_sizes, int n_in,
                              void* d_out, int out_size, void* d_ws, size_t ws_size,
                              hipStream_t stream)
{
    const float* x    = (const float*)d_in[0];
    const float* ef   = (const float*)d_in[1];
    const float* flow = (const float*)d_in[2];
    const float* w1   = (const float*)d_in[3];
    const float* b1   = (const float*)d_in[4];
    const float* w2   = (const float*)d_in[5];
    const float* b2   = (const float*)d_in[6];
    const float* w3   = (const float*)d_in[7];
    const float* b3   = (const float*)d_in[8];
    const float* wk   = (const float*)d_in[9];
    float* out = (float*)d_out;

    // Workspace layout (floats; every region size divisible by 4 -> 16B align):
    //   h1 2,097,152 | h2 2,097,152 | om 14,155,776 | val 18,874,368
    //   wt1 73,728 | wt2 36,864 | w3h 248,832 halves (124,416 slots)
    //   wkT 36,864 | [part 8,388,608 if ws_size permits, else alias om]
    float*    h1  = (float*)d_ws;
    float*    h2  = h1 + (size_t)B_ * C_ * HW_;
    float*    om  = h2 + (size_t)B_ * C_ * HW_;
    float*    val = om + (size_t)B_ * OFFC_ * HW_;
    float*    wt1 = val + (size_t)B_ * R_ * HW_;
    float*    wt2 = wt1 + 1152 * 64;
    _Float16* w3h = (_Float16*)(wt2 + 576 * 64);      // 432*576 f16
    float*    wkT = (float*)(w3h + OFFC_ * R_);
    float*    end = wkT + 576 * 64;
    const size_t need_sep = ((size_t)(end - h1) + (size_t)RS_ * B_ * C_ * HW_) * 4;
    float*    part = (ws_size >= need_sep) ? end : om;  // constant per deployment

    transpose_w_k<64, 1152><<<dim3((64 * 1152 + 255) / 256), 256, 0, stream>>>(w1, wt1);
    transpose_w_k<64, 576><<<dim3((64 * 576 + 255) / 256), 256, 0, stream>>>(w2, wt2);
    prep_w3h_k<<<dim3((OFFC_ * R_ + 255) / 256), 256, 0, stream>>>(w3, w3h);
    transpose_w_k<64, 576><<<dim3((64 * 576 + 255) / 256), 256, 0, stream>>>(wk, wkT);

    dim3 blk(16, 16, 1);
    conv3x3_leaky_k<2 * C_, C_, 1><<<dim3(W_ / 16, H_ / 16, B_ * (C_ / 16)), blk, 0, stream>>>(ef, wt1, b1, h1);
    conv3x3_leaky_k<C_, C_, 1><<<dim3(W_ / 16, H_ / 16, B_ * (C_ / 16)), blk, 0, stream>>>(h1, wt2, b2, h2);

    conv3_mfma_k<<<dim3(B_ * H_, 3), 256, 0, stream>>>(h2, w3h, b3, flow, om);

    gather_k<<<dim3(HW_ / 256, B_ * DG_ * KK_), 256, 0, stream>>>(x, om, val);
    einsum_part_k<<<dim3(HW_ / 256, B_ * 4 * RS_), 256, 0, stream>>>(val, wkT, part);
    combine_k<<<dim3((B_ * C_ * HW_ / 4 + 255) / 256), 256, 0, stream>>>((const float4*)part, (float4*)out);
}

// Round 8
// 439.307 us; speedup vs baseline: 1.2821x; 1.1825x over previous
//
#include <hip/hip_runtime.h>
#include <math.h>

// Problem constants (fixed by setup_inputs)
constexpr int B_   = 2;
constexpr int C_   = 64;
constexpr int H_   = 128;
constexpr int W_   = 128;
constexpr int HW_  = H_ * W_;
constexpr int DG_  = 16;   // deformable groups
constexpr int KK_  = 9;    // 3x3 taps
constexpr int CG_  = 4;    // channels per group = C/DG
constexpr int OFFC_ = 3 * KK_ * DG_;  // 432
constexpr int R_   = C_ * KK_;        // 576 reduction length (tap-major K)
constexpr int RS_  = 4;               // einsum r-slices
constexpr int RL_  = R_ / RS_;        // 144 per slice

typedef _Float16 half8 __attribute__((ext_vector_type(8)));  // 8 f16 = 4 VGPR
typedef float floatx4 __attribute__((ext_vector_type(4)));   // MFMA acc

// ---------------------------------------------------------------------------
// Weight transpose: in[OC][IC9] -> out[IC9][OC]  (OC contiguous -> one
// s_load_dwordx16 per 16-chan chunk instead of 16 strided s_load_dword).
// ---------------------------------------------------------------------------
template <int OC, int IC9>
__global__ __launch_bounds__(256) void transpose_w_k(
    const float* __restrict__ in, float* __restrict__ out)
{
    const int j = blockIdx.x * 256 + threadIdx.x;
    if (j >= OC * IC9) return;
    const int row = j / OC;   // ic*9 + tap
    const int col = j - row * OC;
    out[j] = in[(size_t)col * IC9 + row];
}

// ---------------------------------------------------------------------------
// w3 prep for no-LDS MFMA: w3A[(t*2+h)*432 + oc][j] = f16(w3[oc][(h*32+j)*9+t])
// A-fragment load becomes 16 rows x 64 B = fully coalesced 1 KB / instr.
// ---------------------------------------------------------------------------
__global__ __launch_bounds__(256) void prep_w3A_k(
    const float* __restrict__ w3, _Float16* __restrict__ w3A)
{
    const int j = blockIdx.x * 256 + threadIdx.x;   // slab*432*32 + oc*32 + jj
    if (j >= 18 * OFFC_ * 32) return;
    const int slab = j / (OFFC_ * 32);
    const int rem  = j - slab * (OFFC_ * 32);
    const int oc   = rem >> 5;
    const int jj   = rem & 31;
    const int t    = slab >> 1;
    const int h    = slab & 1;
    const int ic   = h * 32 + jj;
    w3A[j] = (_Float16)w3[(size_t)oc * R_ + ic * 9 + t];
}

// ---------------------------------------------------------------------------
// Direct 3x3 conv, pad=1. Thread: PX pixels x 16 out chans.
// NHWC=true: write f16 NHWC (outh[pix][oc], 32 B contiguous per thread) for
// consumption by the MFMA conv3 as its B operand. Else fp32 NCHW.
// ---------------------------------------------------------------------------
template <int CIN, int COUT, int PX, bool NHWC>
__global__ __launch_bounds__(256) void conv3x3_leaky_k(
    const float* __restrict__ in, const float* __restrict__ wt,
    const float* __restrict__ bias, float* __restrict__ out,
    _Float16* __restrict__ outh)
{
    const int xp = blockIdx.x * 16 + threadIdx.x;
    const int yb = (blockIdx.y * 16 + threadIdx.y) * PX;
    const int z  = blockIdx.z;
    constexpr int NCHUNK = COUT / 16;
    const int b   = z / NCHUNK;
    const int ocb = (z % NCHUNK) * 16;

    float acc[PX][16];
#pragma unroll
    for (int p = 0; p < PX; ++p)
#pragma unroll
        for (int o = 0; o < 16; ++o) acc[p][o] = bias[ocb + o];

    const bool vxm = (xp - 1 >= 0);
    const bool vxp = (xp + 1 < W_);
    bool vr[PX + 2];
#pragma unroll
    for (int r = 0; r < PX + 2; ++r)
        vr[r] = ((unsigned)(yb + r - 1) < (unsigned)H_);

    const float* inb = in + (size_t)b * CIN * HW_;
    for (int ic = 0; ic < CIN; ++ic) {
        const float* inc = inb + (size_t)ic * HW_;
        float rv[PX + 2][3];
#pragma unroll
        for (int r = 0; r < PX + 2; ++r) {
            const int yy = yb + r - 1;
            const float* rowp = inc + yy * W_ + xp;
            rv[r][0] = (vr[r] && vxm) ? rowp[-1] : 0.f;
            rv[r][1] = vr[r] ? rowp[0] : 0.f;
            rv[r][2] = (vr[r] && vxp) ? rowp[1] : 0.f;
        }
        const float* wrow = wt + (size_t)(ic * 9) * COUT + ocb;
#pragma unroll
        for (int t = 0; t < 9; ++t) {
            float wv[16];
#pragma unroll
            for (int o = 0; o < 16; ++o) wv[o] = wrow[(size_t)t * COUT + o];
#pragma unroll
            for (int p = 0; p < PX; ++p) {
                const float v = rv[p + t / 3][t % 3];
#pragma unroll
                for (int o = 0; o < 16; ++o)
                    acc[p][o] = fmaf(v, wv[o], acc[p][o]);
            }
        }
    }

#pragma unroll
    for (int p = 0; p < PX; ++p) {
        const int pix = (yb + p) * W_ + xp;
        if (NHWC) {
            half8 v0, v1;
#pragma unroll
            for (int o = 0; o < 8; ++o) {
                float r0 = acc[p][o];
                float r1 = acc[p][8 + o];
                r0 = (r0 >= 0.f) ? r0 : 0.1f * r0;
                r1 = (r1 >= 0.f) ? r1 : 0.1f * r1;
                v0[o] = (_Float16)r0;
                v1[o] = (_Float16)r1;
            }
            _Float16* dst = outh + ((size_t)b * HW_ + pix) * COUT + ocb;
            *(half8*)dst       = v0;
            *(half8*)(dst + 8) = v1;
        } else {
#pragma unroll
            for (int o = 0; o < 16; ++o) {
                float r = acc[p][o];
                r = (r >= 0.f) ? r : 0.1f * r;
                out[((size_t)(b * COUT + ocb + o)) * HW_ + pix] = r;
            }
        }
    }
}

// ---------------------------------------------------------------------------
// Conv3 via f16 MFMA implicit GEMM — NO LDS, NO BARRIERS.
// GEMM: D[oc][pix] = sum_k W[oc][k] * X[k][pix], K = 576 (18 slabs of 32).
// A = weights from w3A (coalesced 1 KB/load), B = pixels from h2n NHWC f16
// (16 B/lane, L1/L2-resident, per-lane OOB predication for the halo).
// Block: one image row (128 px) x 48 oc; 4 waves x 32 px; 3 m-frags x 2
// n-frags = 24 acc VGPRs. Grid 256 x 9 = 2304 blocks -> 9 blocks/CU.
// Epilogue fuses bias + 10*tanh + flow add / sigmoid, writes omap.
// ---------------------------------------------------------------------------
__global__ __launch_bounds__(256) void conv3_mfma_k(
    const _Float16* __restrict__ h2n, const _Float16* __restrict__ w3A,
    const float* __restrict__ bias, const float* __restrict__ flow,
    float* __restrict__ omap)
{
    const int tid  = threadIdx.x;
    const int lane = tid & 63;
    const int wv   = tid >> 6;       // wave id 0..3
    const int l15  = lane & 15;
    const int quad = lane >> 4;

    const int row = blockIdx.x;      // b*128 + y
    const int b   = row >> 7;
    const int y   = row & 127;
    const int m0  = blockIdx.y * 48; // oc tile base

    floatx4 acc[3][2];
#pragma unroll
    for (int mf = 0; mf < 3; ++mf)
#pragma unroll
        for (int nf = 0; nf < 2; ++nf)
            acc[mf][nf] = (floatx4){0.f, 0.f, 0.f, 0.f};

    const _Float16* h2b = h2n + (size_t)b * HW_ * C_;

    for (int t = 0; t < 9; ++t) {
        const int dy = t / 3, dx = t % 3;
        const int yy = y + dy - 1;
        const bool vy = ((unsigned)yy < (unsigned)H_);
#pragma unroll
        for (int h = 0; h < 2; ++h) {        // two 32-ic halves of K
            half8 bfr[2];
#pragma unroll
            for (int nf = 0; nf < 2; ++nf) {
                const int xx = wv * 32 + nf * 16 + l15 + dx - 1;
                half8 v = (half8){0, 0, 0, 0, 0, 0, 0, 0};
                if (vy && (unsigned)xx < (unsigned)W_)
                    v = *(const half8*)&h2b[((size_t)yy * W_ + xx) * C_ + h * 32 + quad * 8];
                bfr[nf] = v;
            }
            const _Float16* wbase = w3A + ((size_t)(t * 2 + h) * OFFC_ + m0) * 32;
#pragma unroll
            for (int mf = 0; mf < 3; ++mf) {
                const half8 afr = *(const half8*)&wbase[(mf * 16 + l15) * 32 + quad * 8];
#pragma unroll
                for (int nf = 0; nf < 2; ++nf)
                    acc[mf][nf] = __builtin_amdgcn_mfma_f32_16x16x32_f16(
                        afr, bfr[nf], acc[mf][nf], 0, 0, 0);
            }
        }
    }

    // ---- epilogue: bias + offset/mask transform, coalesced omap stores ----
#pragma unroll
    for (int mf = 0; mf < 3; ++mf) {
#pragma unroll
        for (int nf = 0; nf < 2; ++nf) {
#pragma unroll
            for (int reg = 0; reg < 4; ++reg) {
                const int oc  = m0 + mf * 16 + quad * 4 + reg;
                const int px  = wv * 32 + nf * 16 + l15;
                const int pix = y * W_ + px;
                float val = acc[mf][nf][reg] + bias[oc];
                int g, k, slot;
                if (oc < 2 * DG_ * KK_) {          // offset channels
                    g = oc / 18;
                    const int rem = oc - g * 18;
                    k = rem >> 1;
                    slot = rem & 1;                 // 0 = y, 1 = x
                    const float fl = flow[(size_t)(b * 2 + (1 - slot)) * HW_ + pix];
                    val = 10.f * tanhf(val) + fl;
                } else {                            // mask channels
                    const int c = oc - 2 * DG_ * KK_;
                    g = c / 9;
                    k = c - g * 9;
                    slot = 2;
                    val = 1.f / (1.f + expf(-val));
                }
                omap[((size_t)((b * DG_ * KK_ + g * KK_ + k) * 3 + slot)) * HW_ + pix] = val;
            }
        }
    }
}

// ---------------------------------------------------------------------------
// Phase A: bilinear gather. Thread = (pixel, one (g,k) tap).
// val[b][(g*4+c)*9 + k][pix] = masked bilinear sample.
// ---------------------------------------------------------------------------
__global__ __launch_bounds__(256) void gather_k(
    const float* __restrict__ x, const float* __restrict__ omap,
    float* __restrict__ val)
{
    const int pix = blockIdx.x * 256 + threadIdx.x;
    const int z   = blockIdx.y;               // b * 144 + g*9 + k
    const int b   = z / (DG_ * KK_);
    const int gk  = z - b * DG_ * KK_;
    const int g   = gk / KK_;
    const int k   = gk - g * KK_;
    const int yp  = pix >> 7;
    const int xp  = pix & (W_ - 1);

    const size_t obase = ((size_t)(b * DG_ * KK_ + gk) * 3) * HW_ + pix;
    const float oy = omap[obase];
    const float ox = omap[obase + HW_];
    const float m  = omap[obase + 2 * HW_];

    const float py = (float)(yp + (k / 3) - 1) + oy;
    const float px = (float)(xp + (k % 3) - 1) + ox;
    const float y0f = floorf(py);
    const float x0f = floorf(px);
    const float wy = py - y0f;
    const float wx = px - x0f;
    const int y0 = (int)y0f, x0 = (int)x0f;
    const int y1 = y0 + 1,  x1 = x0 + 1;
    const bool vy0 = ((unsigned)y0 < (unsigned)H_);
    const bool vy1 = ((unsigned)y1 < (unsigned)H_);
    const bool vx0 = ((unsigned)x0 < (unsigned)W_);
    const bool vx1 = ((unsigned)x1 < (unsigned)W_);
    const float w00 = vy0 && vx0 ? (1.f - wy) * (1.f - wx) : 0.f;
    const float w01 = vy0 && vx1 ? (1.f - wy) * wx         : 0.f;
    const float w10 = vy1 && vx0 ? wy * (1.f - wx)         : 0.f;
    const float w11 = vy1 && vx1 ? wy * wx                 : 0.f;
    const int i00 = (vy0 && vx0) ? y0 * W_ + x0 : 0;
    const int i01 = (vy0 && vx1) ? y0 * W_ + x1 : 0;
    const int i10 = (vy1 && vx0) ? y1 * W_ + x0 : 0;
    const int i11 = (vy1 && vx1) ? y1 * W_ + x1 : 0;

    const float* xg = x + (size_t)(b * C_ + g * CG_) * HW_;
    float* vg = val + ((size_t)b * R_ + (size_t)(g * CG_) * KK_ + k) * HW_ + pix;
#pragma unroll
    for (int c = 0; c < CG_; ++c) {
        const float* img = xg + (size_t)c * HW_;
        float v = w00 * img[i00] + w01 * img[i01] + w10 * img[i10] + w11 * img[i11];
        vg[(size_t)c * KK_ * HW_] = v * m;
    }
}

// ---------------------------------------------------------------------------
// Phase B1: partial einsum over an r-slice of 144.
// part[slice][b][o][pix] = sum_{r in slice} val[b][r][pix] * wkT[r][o].
// ---------------------------------------------------------------------------
__global__ __launch_bounds__(256) void einsum_part_k(
    const float* __restrict__ val, const float* __restrict__ wkT,
    float* __restrict__ part)
{
    const int pix = blockIdx.x * 256 + threadIdx.x;
    const int z   = blockIdx.y;               // b(2) x ocb(4) x slice(4)
    const int b   = z >> 4;
    const int ocb = ((z >> 2) & 3) * 16;
    const int sl  = z & 3;
    const int r0  = sl * RL_;

    float acc[16];
#pragma unroll
    for (int o = 0; o < 16; ++o) acc[o] = 0.f;

    const float* vb = val + ((size_t)b * R_ + r0) * HW_ + pix;
    const float* wp = wkT + (size_t)r0 * C_ + ocb;
#pragma unroll 4
    for (int r = 0; r < RL_; ++r) {
        const float s = vb[(size_t)r * HW_];
        const float* w = wp + (size_t)r * C_;
#pragma unroll
        for (int o = 0; o < 16; ++o)
            acc[o] = fmaf(s, w[o], acc[o]);
    }

    float* pb = part + (((size_t)(sl * B_ + b)) * C_ + ocb) * HW_ + pix;
#pragma unroll
    for (int o = 0; o < 16; ++o)
        pb[(size_t)o * HW_] = acc[o];
}

// ---------------------------------------------------------------------------
// Phase B2: combine the 4 r-slice partials into d_out (float4 vectorized).
// ---------------------------------------------------------------------------
__global__ __launch_bounds__(256) void combine_k(
    const float4* __restrict__ part, float4* __restrict__ out)
{
    constexpr int N4 = B_ * C_ * HW_ / 4;   // 524288
    const int i = blockIdx.x * 256 + threadIdx.x;
    if (i >= N4) return;
    float4 a = part[i];
    const float4 b = part[i + N4];
    const float4 c = part[i + 2 * N4];
    const float4 d = part[i + 3 * N4];
    a.x += b.x + c.x + d.x;
    a.y += b.y + c.y + d.y;
    a.z += b.z + c.z + d.z;
    a.w += b.w + c.w + d.w;
    out[i] = a;
}

// ---------------------------------------------------------------------------
extern "C" void kernel_launch(void* const* d_in, const int* in_sizes, int n_in,
                              void* d_out, int out_size, void* d_ws, size_t ws_size,
                              hipStream_t stream)
{
    const float* x    = (const float*)d_in[0];
    const float* ef   = (const float*)d_in[1];
    const float* flow = (const float*)d_in[2];
    const float* w1   = (const float*)d_in[3];
    const float* b1   = (const float*)d_in[4];
    const float* w2   = (const float*)d_in[5];
    const float* b2   = (const float*)d_in[6];
    const float* w3   = (const float*)d_in[7];
    const float* b3   = (const float*)d_in[8];
    const float* wk   = (const float*)d_in[9];
    float* out = (float*)d_out;

    // Workspace layout (float slots; all region sizes divisible by 4):
    //   h1 2,097,152 | h2n 1,048,576 (2.1M halves) | om 14,155,776
    //   val 18,874,368 | wt1 73,728 | wt2 36,864
    //   w3A 124,416 (248,832 halves) | wkT 36,864 | [part 8,388,608 optional]
    float*    h1  = (float*)d_ws;
    _Float16* h2n = (_Float16*)(h1 + (size_t)B_ * C_ * HW_);
    float*    om  = (float*)(h2n + (size_t)B_ * HW_ * C_);
    float*    val = om + (size_t)B_ * OFFC_ * HW_;
    float*    wt1 = val + (size_t)B_ * R_ * HW_;
    float*    wt2 = wt1 + 1152 * 64;
    _Float16* w3A = (_Float16*)(wt2 + 576 * 64);      // 18*432*32 f16
    float*    wkT = (float*)(w3A + 18 * OFFC_ * 32);
    float*    end = wkT + 576 * 64;
    const size_t need_sep = ((size_t)(end - h1) + (size_t)RS_ * B_ * C_ * HW_) * 4;
    float*    part = (ws_size >= need_sep) ? end : om;  // constant per deployment

    transpose_w_k<64, 1152><<<dim3((64 * 1152 + 255) / 256), 256, 0, stream>>>(w1, wt1);
    transpose_w_k<64, 576><<<dim3((64 * 576 + 255) / 256), 256, 0, stream>>>(w2, wt2);
    prep_w3A_k<<<dim3((18 * OFFC_ * 32 + 255) / 256), 256, 0, stream>>>(w3, w3A);
    transpose_w_k<64, 576><<<dim3((64 * 576 + 255) / 256), 256, 0, stream>>>(wk, wkT);

    dim3 blk(16, 16, 1);
    conv3x3_leaky_k<2 * C_, C_, 1, false><<<dim3(W_ / 16, H_ / 16, B_ * (C_ / 16)), blk, 0, stream>>>(ef, wt1, b1, h1, nullptr);
    conv3x3_leaky_k<C_, C_, 1, true><<<dim3(W_ / 16, H_ / 16, B_ * (C_ / 16)), blk, 0, stream>>>(h1, wt2, b2, nullptr, h2n);

    conv3_mfma_k<<<dim3(B_ * H_, OFFC_ / 48), 256, 0, stream>>>(h2n, w3A, b3, flow, om);

    gather_k<<<dim3(HW_ / 256, B_ * DG_ * KK_), 256, 0, stream>>>(x, om, val);
    einsum_part_k<<<dim3(HW_ / 256, B_ * 4 * RS_), 256, 0, stream>>>(val, wkT, part);
    combine_k<<<dim3((B_ * C_ * HW_ / 4 + 255) / 256), 256, 0, stream>>>((const float4*)part, (float4*)out);
}

// Round 9
// 364.181 us; speedup vs baseline: 1.5466x; 1.2063x over previous
//
#include <hip/hip_runtime.h>
#include <math.h>

// Problem constants (fixed by setup_inputs)
constexpr int B_   = 2;
constexpr int C_   = 64;
constexpr int H_   = 128;
constexpr int W_   = 128;
constexpr int HW_  = H_ * W_;
constexpr int DG_  = 16;   // deformable groups
constexpr int KK_  = 9;    // 3x3 taps
constexpr int CG_  = 4;    // channels per group = C/DG
constexpr int OFFC_ = 3 * KK_ * DG_;  // 432
constexpr int R_   = C_ * KK_;        // 576 reduction length (tap-major K)
constexpr int RS_  = 4;               // einsum r-slices
constexpr int RL_  = R_ / RS_;        // 144 per slice

typedef _Float16 half8 __attribute__((ext_vector_type(8)));  // 8 f16 = 4 VGPR
typedef _Float16 half4 __attribute__((ext_vector_type(4)));  // 8-byte store
typedef float floatx4 __attribute__((ext_vector_type(4)));   // MFMA acc

// ---------------------------------------------------------------------------
// Weight transpose: in[OC][IC9] -> out[IC9][OC] (for the fp32 einsum).
// ---------------------------------------------------------------------------
template <int OC, int IC9>
__global__ __launch_bounds__(256) void transpose_w_k(
    const float* __restrict__ in, float* __restrict__ out)
{
    const int j = blockIdx.x * 256 + threadIdx.x;
    if (j >= OC * IC9) return;
    const int row = j / OC;   // ic*9 + tap
    const int col = j - row * OC;
    out[j] = in[(size_t)col * IC9 + row];
}

// ---------------------------------------------------------------------------
// Generic MFMA A-operand prep: wA[(t*CH+h)*OC + oc][j] = f16(w[oc][(h*32+j)*9+t])
// (CH = CIN/32). A-fragment load = 16 rows x 64 B = fully coalesced 1 KB.
// ---------------------------------------------------------------------------
template <int OC, int CIN>
__global__ __launch_bounds__(256) void prep_wA_k(
    const float* __restrict__ w, _Float16* __restrict__ wA)
{
    constexpr int CH = CIN / 32;
    const int j = blockIdx.x * 256 + threadIdx.x;   // slab*OC*32 + oc*32 + jj
    if (j >= 9 * CH * OC * 32) return;
    const int slab = j / (OC * 32);
    const int rem  = j - slab * (OC * 32);
    const int oc   = rem >> 5;
    const int jj   = rem & 31;
    const int t    = slab / CH;
    const int h    = slab - t * CH;
    const int ic   = h * 32 + jj;
    wA[j] = (_Float16)w[(size_t)oc * (CIN * 9) + ic * 9 + t];
}

// ---------------------------------------------------------------------------
// NCHW fp32 -> NHWC f16 (for conv1's B operand).
// ---------------------------------------------------------------------------
template <int CC>
__global__ __launch_bounds__(256) void nchw2nhwc_f16_k(
    const float* __restrict__ in, _Float16* __restrict__ outh)
{
    const int pix = blockIdx.x * 256 + threadIdx.x;
    const int b   = blockIdx.y;
    const float* ib = in + (size_t)b * CC * HW_ + pix;
    _Float16* ob = outh + ((size_t)b * HW_ + pix) * CC;
#pragma unroll
    for (int c0 = 0; c0 < CC; c0 += 8) {
        half8 v;
#pragma unroll
        for (int j = 0; j < 8; ++j)
            v[j] = (_Float16)ib[(size_t)(c0 + j) * HW_];
        *(half8*)&ob[c0] = v;
    }
}

// ---------------------------------------------------------------------------
// Conv1/conv2 (CIN -> 64) via f16 MFMA, no LDS, no barriers, fused leaky.
// Tiny tiles for occupancy: block = 64 px x 16 oc, wave = 16 px x 16 oc,
// ONE acc fragment (4 VGPRs). Grid (B*H*2, 4) = 2048 blocks -> 32 waves/CU.
// B = NHWC f16 input (16 B/lane, L1/L2-resident, halo predicated);
// A = prepped weights (coalesced 1 KB/load). Output NHWC f16.
// ---------------------------------------------------------------------------
template <int CIN>
__global__ __launch_bounds__(256) void conv12_mfma_k(
    const _Float16* __restrict__ inn, const _Float16* __restrict__ wA,
    const float* __restrict__ bias, _Float16* __restrict__ outn)
{
    constexpr int CH = CIN / 32;
    const int tid  = threadIdx.x;
    const int lane = tid & 63;
    const int wv   = tid >> 6;
    const int l15  = lane & 15;
    const int quad = lane >> 4;

    const int zx   = blockIdx.x;          // (b*H + y)*2 + half64
    const int row  = zx >> 1;
    const int b    = row >> 7;
    const int y    = row & 127;
    const int px0  = (zx & 1) * 64 + wv * 16;
    const int oct  = blockIdx.y;          // oc tile (16 chans)

    floatx4 acc = (floatx4){0.f, 0.f, 0.f, 0.f};
    const _Float16* inb = inn + (size_t)b * HW_ * CIN;

    for (int t = 0; t < 9; ++t) {
        const int dy = t / 3, dx = t % 3;
        const int yy = y + dy - 1;
        const int xx = px0 + l15 + dx - 1;
        const bool v = ((unsigned)yy < (unsigned)H_) && ((unsigned)xx < (unsigned)W_);
        const _Float16* bp = inb + ((size_t)yy * W_ + xx) * CIN + quad * 8;
        const _Float16* ap = wA + ((size_t)(t * CH) * 64 + oct * 16 + l15) * 32 + quad * 8;
#pragma unroll
        for (int h = 0; h < CH; ++h) {
            half8 bfr = (half8){0, 0, 0, 0, 0, 0, 0, 0};
            if (v) bfr = *(const half8*)&bp[h * 32];
            const half8 afr = *(const half8*)&ap[(size_t)h * 64 * 32];
            acc = __builtin_amdgcn_mfma_f32_16x16x32_f16(afr, bfr, acc, 0, 0, 0);
        }
    }

    // epilogue: leaky ReLU, f16 NHWC store (8 B/lane)
    const int pix = y * W_ + px0 + l15;
    half4 v4;
#pragma unroll
    for (int reg = 0; reg < 4; ++reg) {
        float r = acc[reg] + bias[oct * 16 + quad * 4 + reg];
        r = (r >= 0.f) ? r : 0.1f * r;
        v4[reg] = (_Float16)r;
    }
    *(half4*)&outn[((size_t)b * HW_ + pix) * 64 + oct * 16 + quad * 4] = v4;
}

// ---------------------------------------------------------------------------
// Conv3 via f16 MFMA implicit GEMM — NO LDS, NO BARRIERS.
// GEMM: D[oc][pix] = sum_k W[oc][k] * X[k][pix], K = 576 (18 slabs of 32).
// Block: one image row (128 px) x 48 oc; grid 256 x 9 = 2304 blocks.
// Epilogue fuses bias + 10*tanh + flow add / sigmoid, writes omap.
// ---------------------------------------------------------------------------
__global__ __launch_bounds__(256) void conv3_mfma_k(
    const _Float16* __restrict__ h2n, const _Float16* __restrict__ w3A,
    const float* __restrict__ bias, const float* __restrict__ flow,
    float* __restrict__ omap)
{
    const int tid  = threadIdx.x;
    const int lane = tid & 63;
    const int wv   = tid >> 6;       // wave id 0..3
    const int l15  = lane & 15;
    const int quad = lane >> 4;

    const int row = blockIdx.x;      // b*128 + y
    const int b   = row >> 7;
    const int y   = row & 127;
    const int m0  = blockIdx.y * 48; // oc tile base

    floatx4 acc[3][2];
#pragma unroll
    for (int mf = 0; mf < 3; ++mf)
#pragma unroll
        for (int nf = 0; nf < 2; ++nf)
            acc[mf][nf] = (floatx4){0.f, 0.f, 0.f, 0.f};

    const _Float16* h2b = h2n + (size_t)b * HW_ * C_;

    for (int t = 0; t < 9; ++t) {
        const int dy = t / 3, dx = t % 3;
        const int yy = y + dy - 1;
        const bool vy = ((unsigned)yy < (unsigned)H_);
#pragma unroll
        for (int h = 0; h < 2; ++h) {        // two 32-ic halves of K
            half8 bfr[2];
#pragma unroll
            for (int nf = 0; nf < 2; ++nf) {
                const int xx = wv * 32 + nf * 16 + l15 + dx - 1;
                half8 v = (half8){0, 0, 0, 0, 0, 0, 0, 0};
                if (vy && (unsigned)xx < (unsigned)W_)
                    v = *(const half8*)&h2b[((size_t)yy * W_ + xx) * C_ + h * 32 + quad * 8];
                bfr[nf] = v;
            }
            const _Float16* wbase = w3A + ((size_t)(t * 2 + h) * OFFC_ + m0) * 32;
#pragma unroll
            for (int mf = 0; mf < 3; ++mf) {
                const half8 afr = *(const half8*)&wbase[(mf * 16 + l15) * 32 + quad * 8];
#pragma unroll
                for (int nf = 0; nf < 2; ++nf)
                    acc[mf][nf] = __builtin_amdgcn_mfma_f32_16x16x32_f16(
                        afr, bfr[nf], acc[mf][nf], 0, 0, 0);
            }
        }
    }

    // ---- epilogue: bias + offset/mask transform, coalesced omap stores ----
#pragma unroll
    for (int mf = 0; mf < 3; ++mf) {
#pragma unroll
        for (int nf = 0; nf < 2; ++nf) {
#pragma unroll
            for (int reg = 0; reg < 4; ++reg) {
                const int oc  = m0 + mf * 16 + quad * 4 + reg;
                const int px  = wv * 32 + nf * 16 + l15;
                const int pix = y * W_ + px;
                float val = acc[mf][nf][reg] + bias[oc];
                int g, k, slot;
                if (oc < 2 * DG_ * KK_) {          // offset channels
                    g = oc / 18;
                    const int rem = oc - g * 18;
                    k = rem >> 1;
                    slot = rem & 1;                 // 0 = y, 1 = x
                    const float fl = flow[(size_t)(b * 2 + (1 - slot)) * HW_ + pix];
                    val = 10.f * tanhf(val) + fl;
                } else {                            // mask channels
                    const int c = oc - 2 * DG_ * KK_;
                    g = c / 9;
                    k = c - g * 9;
                    slot = 2;
                    val = 1.f / (1.f + expf(-val));
                }
                omap[((size_t)((b * DG_ * KK_ + g * KK_ + k) * 3 + slot)) * HW_ + pix] = val;
            }
        }
    }
}

// ---------------------------------------------------------------------------
// Phase A: bilinear gather. Thread = (pixel, one (g,k) tap).
// val[b][(g*4+c)*9 + k][pix] = masked bilinear sample.
// ---------------------------------------------------------------------------
__global__ __launch_bounds__(256) void gather_k(
    const float* __restrict__ x, const float* __restrict__ omap,
    float* __restrict__ val)
{
    const int pix = blockIdx.x * 256 + threadIdx.x;
    const int z   = blockIdx.y;               // b * 144 + g*9 + k
    const int b   = z / (DG_ * KK_);
    const int gk  = z - b * DG_ * KK_;
    const int g   = gk / KK_;
    const int k   = gk - g * KK_;
    const int yp  = pix >> 7;
    const int xp  = pix & (W_ - 1);

    const size_t obase = ((size_t)(b * DG_ * KK_ + gk) * 3) * HW_ + pix;
    const float oy = omap[obase];
    const float ox = omap[obase + HW_];
    const float m  = omap[obase + 2 * HW_];

    const float py = (float)(yp + (k / 3) - 1) + oy;
    const float px = (float)(xp + (k % 3) - 1) + ox;
    const float y0f = floorf(py);
    const float x0f = floorf(px);
    const float wy = py - y0f;
    const float wx = px - x0f;
    const int y0 = (int)y0f, x0 = (int)x0f;
    const int y1 = y0 + 1,  x1 = x0 + 1;
    const bool vy0 = ((unsigned)y0 < (unsigned)H_);
    const bool vy1 = ((unsigned)y1 < (unsigned)H_);
    const bool vx0 = ((unsigned)x0 < (unsigned)W_);
    const bool vx1 = ((unsigned)x1 < (unsigned)W_);
    const float w00 = vy0 && vx0 ? (1.f - wy) * (1.f - wx) : 0.f;
    const float w01 = vy0 && vx1 ? (1.f - wy) * wx         : 0.f;
    const float w10 = vy1 && vx0 ? wy * (1.f - wx)         : 0.f;
    const float w11 = vy1 && vx1 ? wy * wx                 : 0.f;
    const int i00 = (vy0 && vx0) ? y0 * W_ + x0 : 0;
    const int i01 = (vy0 && vx1) ? y0 * W_ + x1 : 0;
    const int i10 = (vy1 && vx0) ? y1 * W_ + x0 : 0;
    const int i11 = (vy1 && vx1) ? y1 * W_ + x1 : 0;

    const float* xg = x + (size_t)(b * C_ + g * CG_) * HW_;
    float* vg = val + ((size_t)b * R_ + (size_t)(g * CG_) * KK_ + k) * HW_ + pix;
#pragma unroll
    for (int c = 0; c < CG_; ++c) {
        const float* img = xg + (size_t)c * HW_;
        float v = w00 * img[i00] + w01 * img[i01] + w10 * img[i10] + w11 * img[i11];
        vg[(size_t)c * KK_ * HW_] = v * m;
    }
}

// ---------------------------------------------------------------------------
// Phase B1: partial einsum over an r-slice of 144.
// part[slice][b][o][pix] = sum_{r in slice} val[b][r][pix] * wkT[r][o].
// ---------------------------------------------------------------------------
__global__ __launch_bounds__(256) void einsum_part_k(
    const float* __restrict__ val, const float* __restrict__ wkT,
    float* __restrict__ part)
{
    const int pix = blockIdx.x * 256 + threadIdx.x;
    const int z   = blockIdx.y;               // b(2) x ocb(4) x slice(4)
    const int b   = z >> 4;
    const int ocb = ((z >> 2) & 3) * 16;
    const int sl  = z & 3;
    const int r0  = sl * RL_;

    float acc[16];
#pragma unroll
    for (int o = 0; o < 16; ++o) acc[o] = 0.f;

    const float* vb = val + ((size_t)b * R_ + r0) * HW_ + pix;
    const float* wp = wkT + (size_t)r0 * C_ + ocb;
#pragma unroll 4
    for (int r = 0; r < RL_; ++r) {
        const float s = vb[(size_t)r * HW_];
        const float* w = wp + (size_t)r * C_;
#pragma unroll
        for (int o = 0; o < 16; ++o)
            acc[o] = fmaf(s, w[o], acc[o]);
    }

    float* pb = part + (((size_t)(sl * B_ + b)) * C_ + ocb) * HW_ + pix;
#pragma unroll
    for (int o = 0; o < 16; ++o)
        pb[(size_t)o * HW_] = acc[o];
}

// ---------------------------------------------------------------------------
// Phase B2: combine the 4 r-slice partials into d_out (float4 vectorized).
// ---------------------------------------------------------------------------
__global__ __launch_bounds__(256) void combine_k(
    const float4* __restrict__ part, float4* __restrict__ out)
{
    constexpr int N4 = B_ * C_ * HW_ / 4;   // 524288
    const int i = blockIdx.x * 256 + threadIdx.x;
    if (i >= N4) return;
    float4 a = part[i];
    const float4 b = part[i + N4];
    const float4 c = part[i + 2 * N4];
    const float4 d = part[i + 3 * N4];
    a.x += b.x + c.x + d.x;
    a.y += b.y + c.y + d.y;
    a.z += b.z + c.z + d.z;
    a.w += b.w + c.w + d.w;
    out[i] = a;
}

// ---------------------------------------------------------------------------
extern "C" void kernel_launch(void* const* d_in, const int* in_sizes, int n_in,
                              void* d_out, int out_size, void* d_ws, size_t ws_size,
                              hipStream_t stream)
{
    const float* x    = (const float*)d_in[0];
    const float* ef   = (const float*)d_in[1];
    const float* flow = (const float*)d_in[2];
    const float* w1   = (const float*)d_in[3];
    const float* b1   = (const float*)d_in[4];
    const float* w2   = (const float*)d_in[5];
    const float* b2   = (const float*)d_in[6];
    const float* w3   = (const float*)d_in[7];
    const float* b3   = (const float*)d_in[8];
    const float* wk   = (const float*)d_in[9];
    float* out = (float*)d_out;

    // Workspace layout (float slots; all region sizes divisible by 4):
    //   om 14,155,776 | val 18,874,368 | ef_n 2,097,152 | h1n 1,048,576
    //   h2n 1,048,576 | w1A 36,864 | w2A 18,432 | w3A 124,416 | wkT 36,864
    //   [part 8,388,608 if ws permits, else alias om]
    float*    om   = (float*)d_ws;
    float*    val  = om + (size_t)B_ * OFFC_ * HW_;
    _Float16* ef_n = (_Float16*)(val + (size_t)B_ * R_ * HW_);
    _Float16* h1n  = ef_n + (size_t)B_ * HW_ * 128;
    _Float16* h2n  = h1n + (size_t)B_ * HW_ * 64;
    _Float16* w1A  = h2n + (size_t)B_ * HW_ * 64;
    _Float16* w2A  = w1A + 64 * 128 * 9;
    _Float16* w3A  = w2A + 64 * 64 * 9;
    float*    wkT  = (float*)(w3A + OFFC_ * 64 * 9);
    float*    end  = wkT + 576 * 64;
    const size_t need_sep = ((size_t)(end - om) + (size_t)RS_ * B_ * C_ * HW_) * 4;
    float*    part = (ws_size >= need_sep) ? end : om;  // constant per deployment

    prep_wA_k<64, 128><<<dim3((64 * 128 * 9 + 255) / 256), 256, 0, stream>>>(w1, w1A);
    prep_wA_k<64, 64><<<dim3((64 * 64 * 9 + 255) / 256), 256, 0, stream>>>(w2, w2A);
    prep_wA_k<OFFC_, 64><<<dim3((OFFC_ * 64 * 9 + 255) / 256), 256, 0, stream>>>(w3, w3A);
    transpose_w_k<64, 576><<<dim3((64 * 576 + 255) / 256), 256, 0, stream>>>(wk, wkT);
    nchw2nhwc_f16_k<128><<<dim3(HW_ / 256, B_), 256, 0, stream>>>(ef, ef_n);

    conv12_mfma_k<128><<<dim3(B_ * H_ * 2, 4), 256, 0, stream>>>(ef_n, w1A, b1, h1n);
    conv12_mfma_k<64><<<dim3(B_ * H_ * 2, 4), 256, 0, stream>>>(h1n, w2A, b2, h2n);
    conv3_mfma_k<<<dim3(B_ * H_, OFFC_ / 48), 256, 0, stream>>>(h2n, w3A, b3, flow, om);

    gather_k<<<dim3(HW_ / 256, B_ * DG_ * KK_), 256, 0, stream>>>(x, om, val);
    einsum_part_k<<<dim3(HW_ / 256, B_ * 4 * RS_), 256, 0, stream>>>(val, wkT, part);
    combine_k<<<dim3((B_ * C_ * HW_ / 4 + 255) / 256), 256, 0, stream>>>((const float4*)part, (float4*)out);
}

// Round 10
// 351.395 us; speedup vs baseline: 1.6028x; 1.0364x over previous
//
#include <hip/hip_runtime.h>
#include <math.h>

// Problem constants (fixed by setup_inputs)
constexpr int B_   = 2;
constexpr int C_   = 64;
constexpr int H_   = 128;
constexpr int W_   = 128;
constexpr int HW_  = H_ * W_;
constexpr int DG_  = 16;   // deformable groups
constexpr int KK_  = 9;    // 3x3 taps
constexpr int CG_  = 4;    // channels per group = C/DG
constexpr int OFFC_ = 3 * KK_ * DG_;  // 432
constexpr int R_   = C_ * KK_;        // 576 reduction length

typedef _Float16 half8 __attribute__((ext_vector_type(8)));  // 8 f16 = 4 VGPR
typedef _Float16 half4 __attribute__((ext_vector_type(4)));  // 8-byte store
typedef float floatx4 __attribute__((ext_vector_type(4)));   // MFMA acc

// ---------------------------------------------------------------------------
// Generic MFMA A-operand prep: wA[(t*CH+h)*OC + oc][j] = f16(w[oc][(h*32+j)*9+t])
// (CH = CIN/32). A-fragment load = 16 rows x 64 B = fully coalesced 1 KB.
// ---------------------------------------------------------------------------
template <int OC, int CIN>
__global__ __launch_bounds__(256) void prep_wA_k(
    const float* __restrict__ w, _Float16* __restrict__ wA)
{
    constexpr int CH = CIN / 32;
    const int j = blockIdx.x * 256 + threadIdx.x;   // slab*OC*32 + oc*32 + jj
    if (j >= 9 * CH * OC * 32) return;
    const int slab = j / (OC * 32);
    const int rem  = j - slab * (OC * 32);
    const int oc   = rem >> 5;
    const int jj   = rem & 31;
    const int t    = slab / CH;
    const int h    = slab - t * CH;
    const int ic   = h * 32 + jj;
    wA[j] = (_Float16)w[(size_t)oc * (CIN * 9) + ic * 9 + t];
}

// ---------------------------------------------------------------------------
// Einsum A-operand prep: r = k*64 + gc (gc = g*4+c).  18 slabs of 32.
// wkA[s][oc][jj] = f16(wk[oc][gc*9 + k]) with k = s>>1, gc = (s&1)*32+jj.
// ---------------------------------------------------------------------------
__global__ __launch_bounds__(256) void prep_wkA_k(
    const float* __restrict__ wk, _Float16* __restrict__ wkA)
{
    const int j = blockIdx.x * 256 + threadIdx.x;   // s*2048 + oc*32 + jj
    if (j >= 18 * 64 * 32) return;
    const int s   = j >> 11;
    const int rem = j & 2047;
    const int oc  = rem >> 5;
    const int jj  = rem & 31;
    const int k   = s >> 1;
    const int gc  = (s & 1) * 32 + jj;
    wkA[j] = (_Float16)wk[(size_t)oc * R_ + gc * 9 + k];
}

// ---------------------------------------------------------------------------
// NCHW fp32 -> NHWC f16 (for conv1's B operand).
// ---------------------------------------------------------------------------
template <int CC>
__global__ __launch_bounds__(256) void nchw2nhwc_f16_k(
    const float* __restrict__ in, _Float16* __restrict__ outh)
{
    const int pix = blockIdx.x * 256 + threadIdx.x;
    const int b   = blockIdx.y;
    const float* ib = in + (size_t)b * CC * HW_ + pix;
    _Float16* ob = outh + ((size_t)b * HW_ + pix) * CC;
#pragma unroll
    for (int c0 = 0; c0 < CC; c0 += 8) {
        half8 v;
#pragma unroll
        for (int j = 0; j < 8; ++j)
            v[j] = (_Float16)ib[(size_t)(c0 + j) * HW_];
        *(half8*)&ob[c0] = v;
    }
}

// ---------------------------------------------------------------------------
// Conv1/conv2 (CIN -> 64) via f16 MFMA, no LDS, no barriers, fused leaky.
// Block = 64 px x 16 oc, wave = 16 px x 16 oc, one acc fragment.
// ---------------------------------------------------------------------------
template <int CIN>
__global__ __launch_bounds__(256) void conv12_mfma_k(
    const _Float16* __restrict__ inn, const _Float16* __restrict__ wA,
    const float* __restrict__ bias, _Float16* __restrict__ outn)
{
    constexpr int CH = CIN / 32;
    const int tid  = threadIdx.x;
    const int lane = tid & 63;
    const int wv   = tid >> 6;
    const int l15  = lane & 15;
    const int quad = lane >> 4;

    const int zx   = blockIdx.x;          // (b*H + y)*2 + half64
    const int row  = zx >> 1;
    const int b    = row >> 7;
    const int y    = row & 127;
    const int px0  = (zx & 1) * 64 + wv * 16;
    const int oct  = blockIdx.y;          // oc tile (16 chans)

    floatx4 acc = (floatx4){0.f, 0.f, 0.f, 0.f};
    const _Float16* inb = inn + (size_t)b * HW_ * CIN;

    for (int t = 0; t < 9; ++t) {
        const int dy = t / 3, dx = t % 3;
        const int yy = y + dy - 1;
        const int xx = px0 + l15 + dx - 1;
        const bool v = ((unsigned)yy < (unsigned)H_) && ((unsigned)xx < (unsigned)W_);
        const _Float16* bp = inb + ((size_t)yy * W_ + xx) * CIN + quad * 8;
        const _Float16* ap = wA + ((size_t)(t * CH) * 64 + oct * 16 + l15) * 32 + quad * 8;
#pragma unroll
        for (int h = 0; h < CH; ++h) {
            half8 bfr = (half8){0, 0, 0, 0, 0, 0, 0, 0};
            if (v) bfr = *(const half8*)&bp[h * 32];
            const half8 afr = *(const half8*)&ap[(size_t)h * 64 * 32];
            acc = __builtin_amdgcn_mfma_f32_16x16x32_f16(afr, bfr, acc, 0, 0, 0);
        }
    }

    const int pix = y * W_ + px0 + l15;
    half4 v4;
#pragma unroll
    for (int reg = 0; reg < 4; ++reg) {
        float r = acc[reg] + bias[oct * 16 + quad * 4 + reg];
        r = (r >= 0.f) ? r : 0.1f * r;
        v4[reg] = (_Float16)r;
    }
    *(half4*)&outn[((size_t)b * HW_ + pix) * 64 + oct * 16 + quad * 4] = v4;
}

// ---------------------------------------------------------------------------
// Conv3 via f16 MFMA implicit GEMM — no LDS, no barriers. Widened tile:
// wave = 64 px (nf=4) x 48 oc (mf=3) -> 12 MFMA per 7 loads (was 6 per 5).
// Block = 4 waves = 2 rows x 128 px. Grid (B*H/2, 9) = 1152 blocks.
// Epilogue fuses bias + 10*tanh + flow add / sigmoid, writes omap fp32.
// ---------------------------------------------------------------------------
__global__ __launch_bounds__(256) void conv3_mfma_k(
    const _Float16* __restrict__ h2n, const _Float16* __restrict__ w3A,
    const float* __restrict__ bias, const float* __restrict__ flow,
    float* __restrict__ omap)
{
    const int tid  = threadIdx.x;
    const int lane = tid & 63;
    const int wv   = tid >> 6;       // wave id 0..3
    const int l15  = lane & 15;
    const int quad = lane >> 4;

    const int rp  = blockIdx.x;      // b*64 + y/2
    const int b   = rp >> 6;
    const int y   = ((rp & 63) << 1) | (wv >> 1);
    const int px0 = (wv & 1) * 64;
    const int m0  = blockIdx.y * 48; // oc tile base

    floatx4 acc[3][4];
#pragma unroll
    for (int mf = 0; mf < 3; ++mf)
#pragma unroll
        for (int nf = 0; nf < 4; ++nf)
            acc[mf][nf] = (floatx4){0.f, 0.f, 0.f, 0.f};

    const _Float16* h2b = h2n + (size_t)b * HW_ * C_;

    for (int t = 0; t < 9; ++t) {
        const int dy = t / 3, dx = t % 3;
        const int yy = y + dy - 1;
        const bool vy = ((unsigned)yy < (unsigned)H_);
#pragma unroll
        for (int h = 0; h < 2; ++h) {        // two 32-ic halves of K
            half8 bfr[4];
#pragma unroll
            for (int nf = 0; nf < 4; ++nf) {
                const int xx = px0 + nf * 16 + l15 + dx - 1;
                half8 v = (half8){0, 0, 0, 0, 0, 0, 0, 0};
                if (vy && (unsigned)xx < (unsigned)W_)
                    v = *(const half8*)&h2b[((size_t)yy * W_ + xx) * C_ + h * 32 + quad * 8];
                bfr[nf] = v;
            }
            const _Float16* wbase = w3A + ((size_t)(t * 2 + h) * OFFC_ + m0) * 32;
#pragma unroll
            for (int mf = 0; mf < 3; ++mf) {
                const half8 afr = *(const half8*)&wbase[(mf * 16 + l15) * 32 + quad * 8];
#pragma unroll
                for (int nf = 0; nf < 4; ++nf)
                    acc[mf][nf] = __builtin_amdgcn_mfma_f32_16x16x32_f16(
                        afr, bfr[nf], acc[mf][nf], 0, 0, 0);
            }
        }
    }

#pragma unroll
    for (int mf = 0; mf < 3; ++mf) {
#pragma unroll
        for (int nf = 0; nf < 4; ++nf) {
#pragma unroll
            for (int reg = 0; reg < 4; ++reg) {
                const int oc  = m0 + mf * 16 + quad * 4 + reg;
                const int px  = px0 + nf * 16 + l15;
                const int pix = y * W_ + px;
                float val = acc[mf][nf][reg] + bias[oc];
                int g, k, slot;
                if (oc < 2 * DG_ * KK_) {          // offset channels
                    g = oc / 18;
                    const int rem = oc - g * 18;
                    k = rem >> 1;
                    slot = rem & 1;                 // 0 = y, 1 = x
                    const float fl = flow[(size_t)(b * 2 + (1 - slot)) * HW_ + pix];
                    val = 10.f * tanhf(val) + fl;
                } else {                            // mask channels
                    const int c = oc - 2 * DG_ * KK_;
                    g = c / 9;
                    k = c - g * 9;
                    slot = 2;
                    val = 1.f / (1.f + expf(-val));
                }
                omap[((size_t)((b * DG_ * KK_ + g * KK_ + k) * 3 + slot)) * HW_ + pix] = val;
            }
        }
    }
}

// ---------------------------------------------------------------------------
// Phase A: bilinear gather -> f16 val in [b*HW+pix][r] layout, r = k*64+g*4+c.
// Lane-interleaved: 4 consecutive lanes = 4 g's of one pixel -> their 4
// half4 stores form 32 contiguous bytes (clean HBM write granules).
// Thread = (pixel, g, k) computing 4 channels.
// ---------------------------------------------------------------------------
__global__ __launch_bounds__(256) void gather_k(
    const float* __restrict__ x, const float* __restrict__ omap,
    _Float16* __restrict__ valh)
{
    const int tid = threadIdx.x;
    const int gi  = tid & 3;                  // g within quad group
    const int pl  = tid >> 2;                 // 0..63 pixel local
    const int pix = blockIdx.x * 64 + pl;
    const int zy  = blockIdx.y;               // b*36 + gq*9 + k
    const int b   = zy / 36;
    const int rem = zy - b * 36;
    const int gq  = rem / 9;
    const int k   = rem - gq * 9;
    const int g   = gq * 4 + gi;
    const int yp  = pix >> 7;
    const int xp  = pix & (W_ - 1);

    const size_t obase = ((size_t)((b * DG_ + g) * KK_ + k) * 3) * HW_ + pix;
    const float oy = omap[obase];
    const float ox = omap[obase + HW_];
    const float m  = omap[obase + 2 * HW_];

    const float py = (float)(yp + (k / 3) - 1) + oy;
    const float px = (float)(xp + (k % 3) - 1) + ox;
    const float y0f = floorf(py);
    const float x0f = floorf(px);
    const float wy = py - y0f;
    const float wx = px - x0f;
    const int y0 = (int)y0f, x0 = (int)x0f;
    const int y1 = y0 + 1,  x1 = x0 + 1;
    const bool vy0 = ((unsigned)y0 < (unsigned)H_);
    const bool vy1 = ((unsigned)y1 < (unsigned)H_);
    const bool vx0 = ((unsigned)x0 < (unsigned)W_);
    const bool vx1 = ((unsigned)x1 < (unsigned)W_);
    const float w00 = vy0 && vx0 ? (1.f - wy) * (1.f - wx) : 0.f;
    const float w01 = vy0 && vx1 ? (1.f - wy) * wx         : 0.f;
    const float w10 = vy1 && vx0 ? wy * (1.f - wx)         : 0.f;
    const float w11 = vy1 && vx1 ? wy * wx                 : 0.f;
    const int i00 = (vy0 && vx0) ? y0 * W_ + x0 : 0;
    const int i01 = (vy0 && vx1) ? y0 * W_ + x1 : 0;
    const int i10 = (vy1 && vx0) ? y1 * W_ + x0 : 0;
    const int i11 = (vy1 && vx1) ? y1 * W_ + x1 : 0;

    const float* xg = x + (size_t)(b * C_ + g * CG_) * HW_;
    half4 v4;
#pragma unroll
    for (int c = 0; c < CG_; ++c) {
        const float* img = xg + (size_t)c * HW_;
        float v = w00 * img[i00] + w01 * img[i01] + w10 * img[i10] + w11 * img[i11];
        v4[c] = (_Float16)(v * m);
    }
    *(half4*)&valh[((size_t)(b * HW_ + pix)) * R_ + k * 64 + g * 4] = v4;
}

// ---------------------------------------------------------------------------
// Phase B: einsum via f16 MFMA. out[b,o,pix] = sum_r val[b,pix,r] * wk[o,r].
// M=64 (4 m-frags), wave = 32 px (nf=2), K split 3 ways (6 slabs each) for
// occupancy: grid (256, 3) = 768 blocks. Writes fp32 partials.
// ---------------------------------------------------------------------------
__global__ __launch_bounds__(256) void einsum_mfma_k(
    const _Float16* __restrict__ valh, const _Float16* __restrict__ wkA,
    float* __restrict__ part)
{
    const int tid  = threadIdx.x;
    const int lane = tid & 63;
    const int wv   = tid >> 6;
    const int l15  = lane & 15;
    const int quad = lane >> 4;

    const int pixg0 = blockIdx.x * 128 + wv * 32;   // global pixel (b*HW+pix)
    const int ks    = blockIdx.y;                   // K slice 0..2
    const int s0    = ks * 6;

    floatx4 acc[4][2];
#pragma unroll
    for (int mf = 0; mf < 4; ++mf)
#pragma unroll
        for (int nf = 0; nf < 2; ++nf)
            acc[mf][nf] = (floatx4){0.f, 0.f, 0.f, 0.f};

#pragma unroll
    for (int si = 0; si < 6; ++si) {
        const int s = s0 + si;
        half8 bfr[2];
#pragma unroll
        for (int nf = 0; nf < 2; ++nf)
            bfr[nf] = *(const half8*)&valh[
                (size_t)(pixg0 + nf * 16 + l15) * R_ + s * 32 + quad * 8];
        const _Float16* ap = wkA + (size_t)s * 64 * 32;
#pragma unroll
        for (int mf = 0; mf < 4; ++mf) {
            const half8 afr = *(const half8*)&ap[(mf * 16 + l15) * 32 + quad * 8];
#pragma unroll
            for (int nf = 0; nf < 2; ++nf)
                acc[mf][nf] = __builtin_amdgcn_mfma_f32_16x16x32_f16(
                    afr, bfr[nf], acc[mf][nf], 0, 0, 0);
        }
    }

#pragma unroll
    for (int mf = 0; mf < 4; ++mf) {
#pragma unroll
        for (int nf = 0; nf < 2; ++nf) {
#pragma unroll
            for (int reg = 0; reg < 4; ++reg) {
                const int pixg = pixg0 + nf * 16 + l15;
                const int b    = pixg >> 14;
                const int pix  = pixg & (HW_ - 1);
                const int oc   = mf * 16 + quad * 4 + reg;
                part[(size_t)ks * (B_ * C_ * HW_) +
                     ((size_t)(b * C_ + oc)) * HW_ + pix] = acc[mf][nf][reg];
            }
        }
    }
}

// ---------------------------------------------------------------------------
// Combine the 3 K-slice partials into d_out (float4 vectorized).
// ---------------------------------------------------------------------------
__global__ __launch_bounds__(256) void combine3_k(
    const float4* __restrict__ part, float4* __restrict__ out)
{
    constexpr int N4 = B_ * C_ * HW_ / 4;   // 524288
    const int i = blockIdx.x * 256 + threadIdx.x;
    if (i >= N4) return;
    float4 a = part[i];
    const float4 b = part[i + N4];
    const float4 c = part[i + 2 * N4];
    a.x += b.x + c.x;
    a.y += b.y + c.y;
    a.z += b.z + c.z;
    a.w += b.w + c.w;
    out[i] = a;
}

// ---------------------------------------------------------------------------
extern "C" void kernel_launch(void* const* d_in, const int* in_sizes, int n_in,
                              void* d_out, int out_size, void* d_ws, size_t ws_size,
                              hipStream_t stream)
{
    const float* x    = (const float*)d_in[0];
    const float* ef   = (const float*)d_in[1];
    const float* flow = (const float*)d_in[2];
    const float* w1   = (const float*)d_in[3];
    const float* b1   = (const float*)d_in[4];
    const float* w2   = (const float*)d_in[5];
    const float* b2   = (const float*)d_in[6];
    const float* w3   = (const float*)d_in[7];
    const float* b3   = (const float*)d_in[8];
    const float* wk   = (const float*)d_in[9];
    float* out = (float*)d_out;

    // Workspace (float slots):
    //   om 14,155,776 | valh 9,437,184 (18.9M halves) | ef_n 2,097,152
    //   h1n 1,048,576 | h2n 1,048,576 | w1A 36,864 | w2A 18,432
    //   w3A 124,416 | wkA 18,432 | [part 6,291,456 if ws permits, else alias om]
    float*    om   = (float*)d_ws;
    _Float16* valh = (_Float16*)(om + (size_t)B_ * OFFC_ * HW_);
    _Float16* ef_n = valh + (size_t)B_ * HW_ * R_;
    _Float16* h1n  = ef_n + (size_t)B_ * HW_ * 128;
    _Float16* h2n  = h1n + (size_t)B_ * HW_ * 64;
    _Float16* w1A  = h2n + (size_t)B_ * HW_ * 64;
    _Float16* w2A  = w1A + 64 * 128 * 9;
    _Float16* w3A  = w2A + 64 * 64 * 9;
    _Float16* wkA  = w3A + OFFC_ * 64 * 9;
    float*    end  = (float*)(wkA + 18 * 64 * 32);
    const size_t need_sep = ((size_t)(end - om) + (size_t)3 * B_ * C_ * HW_) * 4;
    float*    part = (ws_size >= need_sep) ? end : om;  // constant per deployment

    prep_wA_k<64, 128><<<dim3((64 * 128 * 9 + 255) / 256), 256, 0, stream>>>(w1, w1A);
    prep_wA_k<64, 64><<<dim3((64 * 64 * 9 + 255) / 256), 256, 0, stream>>>(w2, w2A);
    prep_wA_k<OFFC_, 64><<<dim3((OFFC_ * 64 * 9 + 255) / 256), 256, 0, stream>>>(w3, w3A);
    prep_wkA_k<<<dim3((18 * 64 * 32 + 255) / 256), 256, 0, stream>>>(wk, wkA);
    nchw2nhwc_f16_k<128><<<dim3(HW_ / 256, B_), 256, 0, stream>>>(ef, ef_n);

    conv12_mfma_k<128><<<dim3(B_ * H_ * 2, 4), 256, 0, stream>>>(ef_n, w1A, b1, h1n);
    conv12_mfma_k<64><<<dim3(B_ * H_ * 2, 4), 256, 0, stream>>>(h1n, w2A, b2, h2n);
    conv3_mfma_k<<<dim3(B_ * H_ / 2, 9), 256, 0, stream>>>(h2n, w3A, b3, flow, om);

    gather_k<<<dim3(HW_ / 64, B_ * 4 * KK_), 256, 0, stream>>>(x, om, valh);
    einsum_mfma_k<<<dim3(B_ * HW_ / 128, 3), 256, 0, stream>>>(valh, wkA, part);
    combine3_k<<<dim3((B_ * C_ * HW_ / 4 + 255) / 256), 256, 0, stream>>>((const float4*)part, (float4*)out);
}

// Round 11
// 343.221 us; speedup vs baseline: 1.6410x; 1.0238x over previous
//
#include <hip/hip_runtime.h>
#include <math.h>

// Problem constants (fixed by setup_inputs)
constexpr int B_   = 2;
constexpr int C_   = 64;
constexpr int H_   = 128;
constexpr int W_   = 128;
constexpr int HW_  = H_ * W_;
constexpr int DG_  = 16;   // deformable groups
constexpr int KK_  = 9;    // 3x3 taps
constexpr int CG_  = 4;    // channels per group = C/DG
constexpr int OFFC_ = 3 * KK_ * DG_;  // 432
constexpr int R_   = C_ * KK_;        // 576 reduction length

typedef _Float16 half8 __attribute__((ext_vector_type(8)));  // 8 f16 = 4 VGPR
typedef _Float16 half4 __attribute__((ext_vector_type(4)));  // 8-byte store
typedef float floatx4 __attribute__((ext_vector_type(4)));   // MFMA acc

// ---------------------------------------------------------------------------
// Generic MFMA A-operand prep: wA[(t*CH+h)*OC + oc][j] = f16(w[oc][(h*32+j)*9+t])
// ---------------------------------------------------------------------------
template <int OC, int CIN>
__global__ __launch_bounds__(256) void prep_wA_k(
    const float* __restrict__ w, _Float16* __restrict__ wA)
{
    constexpr int CH = CIN / 32;
    const int j = blockIdx.x * 256 + threadIdx.x;   // slab*OC*32 + oc*32 + jj
    if (j >= 9 * CH * OC * 32) return;
    const int slab = j / (OC * 32);
    const int rem  = j - slab * (OC * 32);
    const int oc   = rem >> 5;
    const int jj   = rem & 31;
    const int t    = slab / CH;
    const int h    = slab - t * CH;
    const int ic   = h * 32 + jj;
    wA[j] = (_Float16)w[(size_t)oc * (CIN * 9) + ic * 9 + t];
}

// ---------------------------------------------------------------------------
// Einsum A-operand prep: r = k*64 + gc (gc = g*4+c).  18 slabs of 32.
// ---------------------------------------------------------------------------
__global__ __launch_bounds__(256) void prep_wkA_k(
    const float* __restrict__ wk, _Float16* __restrict__ wkA)
{
    const int j = blockIdx.x * 256 + threadIdx.x;   // s*2048 + oc*32 + jj
    if (j >= 18 * 64 * 32) return;
    const int s   = j >> 11;
    const int rem = j & 2047;
    const int oc  = rem >> 5;
    const int jj  = rem & 31;
    const int k   = s >> 1;
    const int gc  = (s & 1) * 32 + jj;
    wkA[j] = (_Float16)wk[(size_t)oc * R_ + gc * 9 + k];
}

// ---------------------------------------------------------------------------
// NCHW fp32 -> NHWC f16 (for conv1's B operand).
// ---------------------------------------------------------------------------
template <int CC>
__global__ __launch_bounds__(256) void nchw2nhwc_f16_k(
    const float* __restrict__ in, _Float16* __restrict__ outh)
{
    const int pix = blockIdx.x * 256 + threadIdx.x;
    const int b   = blockIdx.y;
    const float* ib = in + (size_t)b * CC * HW_ + pix;
    _Float16* ob = outh + ((size_t)b * HW_ + pix) * CC;
#pragma unroll
    for (int c0 = 0; c0 < CC; c0 += 8) {
        half8 v;
#pragma unroll
        for (int j = 0; j < 8; ++j)
            v[j] = (_Float16)ib[(size_t)(c0 + j) * HW_];
        *(half8*)&ob[c0] = v;
    }
}

// ---------------------------------------------------------------------------
// Conv1/conv2 (CIN -> 64) via f16 MFMA, no LDS, no barriers, fused leaky.
// ---------------------------------------------------------------------------
template <int CIN>
__global__ __launch_bounds__(256) void conv12_mfma_k(
    const _Float16* __restrict__ inn, const _Float16* __restrict__ wA,
    const float* __restrict__ bias, _Float16* __restrict__ outn)
{
    constexpr int CH = CIN / 32;
    const int tid  = threadIdx.x;
    const int lane = tid & 63;
    const int wv   = tid >> 6;
    const int l15  = lane & 15;
    const int quad = lane >> 4;

    const int zx   = blockIdx.x;          // (b*H + y)*2 + half64
    const int row  = zx >> 1;
    const int b    = row >> 7;
    const int y    = row & 127;
    const int px0  = (zx & 1) * 64 + wv * 16;
    const int oct  = blockIdx.y;          // oc tile (16 chans)

    floatx4 acc = (floatx4){0.f, 0.f, 0.f, 0.f};
    const _Float16* inb = inn + (size_t)b * HW_ * CIN;

    for (int t = 0; t < 9; ++t) {
        const int dy = t / 3, dx = t % 3;
        const int yy = y + dy - 1;
        const int xx = px0 + l15 + dx - 1;
        const bool v = ((unsigned)yy < (unsigned)H_) && ((unsigned)xx < (unsigned)W_);
        const _Float16* bp = inb + ((size_t)yy * W_ + xx) * CIN + quad * 8;
        const _Float16* ap = wA + ((size_t)(t * CH) * 64 + oct * 16 + l15) * 32 + quad * 8;
#pragma unroll
        for (int h = 0; h < CH; ++h) {
            half8 bfr = (half8){0, 0, 0, 0, 0, 0, 0, 0};
            if (v) bfr = *(const half8*)&bp[h * 32];
            const half8 afr = *(const half8*)&ap[(size_t)h * 64 * 32];
            acc = __builtin_amdgcn_mfma_f32_16x16x32_f16(afr, bfr, acc, 0, 0, 0);
        }
    }

    const int pix = y * W_ + px0 + l15;
    half4 v4;
#pragma unroll
    for (int reg = 0; reg < 4; ++reg) {
        float r = acc[reg] + bias[oct * 16 + quad * 4 + reg];
        r = (r >= 0.f) ? r : 0.1f * r;
        v4[reg] = (_Float16)r;
    }
    *(half4*)&outn[((size_t)b * HW_ + pix) * 64 + oct * 16 + quad * 4] = v4;
}

// ---------------------------------------------------------------------------
// Conv3 via f16 MFMA implicit GEMM + LDS-staged CONTIGUOUS epilogue stores.
// Theory (r10 post-mortem): the kernel was write-bound on scattered 64-B
// fp32 segments (~590 GB/s). Here each block stages its 48 oc x 128 px
// result tile in LDS (write-once -> single barrier -> read-only), then
// copies out as 512-B contiguous segments per half-wave (float4).
// Tile: wave = 32 px (nf=2) x 48 oc (mf=3); grid (B*H, 9) = 2304 blocks.
// Fast tanh/sigmoid via __expf + __fdividef (err ~1e-6).
// LDS: 48 x 132 floats = 25.3 KB (stride 132 -> <=2-way bank alias = free).
// ---------------------------------------------------------------------------
__global__ __launch_bounds__(256) void conv3_mfma_k(
    const _Float16* __restrict__ h2n, const _Float16* __restrict__ w3A,
    const float* __restrict__ bias, const float* __restrict__ flow,
    float* __restrict__ omap)
{
    __shared__ __align__(16) float Lds[48 * 132];

    const int tid  = threadIdx.x;
    const int lane = tid & 63;
    const int wv   = tid >> 6;       // wave id 0..3
    const int l15  = lane & 15;
    const int quad = lane >> 4;

    const int row = blockIdx.x;      // b*128 + y
    const int b   = row >> 7;
    const int y   = row & 127;
    const int m0  = blockIdx.y * 48; // oc tile base
    const int px0 = wv * 32;

    floatx4 acc[3][2];
#pragma unroll
    for (int mf = 0; mf < 3; ++mf)
#pragma unroll
        for (int nf = 0; nf < 2; ++nf)
            acc[mf][nf] = (floatx4){0.f, 0.f, 0.f, 0.f};

    const _Float16* h2b = h2n + (size_t)b * HW_ * C_;

    for (int t = 0; t < 9; ++t) {
        const int dy = t / 3, dx = t % 3;
        const int yy = y + dy - 1;
        const bool vy = ((unsigned)yy < (unsigned)H_);
#pragma unroll
        for (int h = 0; h < 2; ++h) {        // two 32-ic halves of K
            half8 bfr[2];
#pragma unroll
            for (int nf = 0; nf < 2; ++nf) {
                const int xx = px0 + nf * 16 + l15 + dx - 1;
                half8 v = (half8){0, 0, 0, 0, 0, 0, 0, 0};
                if (vy && (unsigned)xx < (unsigned)W_)
                    v = *(const half8*)&h2b[((size_t)yy * W_ + xx) * C_ + h * 32 + quad * 8];
                bfr[nf] = v;
            }
            const _Float16* wbase = w3A + ((size_t)(t * 2 + h) * OFFC_ + m0) * 32;
#pragma unroll
            for (int mf = 0; mf < 3; ++mf) {
                const half8 afr = *(const half8*)&wbase[(mf * 16 + l15) * 32 + quad * 8];
#pragma unroll
                for (int nf = 0; nf < 2; ++nf)
                    acc[mf][nf] = __builtin_amdgcn_mfma_f32_16x16x32_f16(
                        afr, bfr[nf], acc[mf][nf], 0, 0, 0);
            }
        }
    }

    // ---- transform + stage to LDS (each thread writes 24 unique slots) ----
#pragma unroll
    for (int mf = 0; mf < 3; ++mf) {
#pragma unroll
        for (int nf = 0; nf < 2; ++nf) {
#pragma unroll
            for (int reg = 0; reg < 4; ++reg) {
                const int ocl = mf * 16 + quad * 4 + reg;   // 0..47
                const int oc  = m0 + ocl;
                const int px  = px0 + nf * 16 + l15;
                float val = acc[mf][nf][reg] + bias[oc];
                if (oc < 2 * DG_ * KK_) {          // offset channels
                    const int slot = oc & 1;        // 0 = y, 1 = x
                    const float fl = flow[(size_t)(b * 2 + (1 - slot)) * HW_ + y * W_ + px];
                    // tanh(x) = 1 - 2/(e^{2x}+1), fast exp + fast divide
                    const float e = __expf(2.f * val);
                    val = 10.f * (1.f - __fdividef(2.f, e + 1.f)) + fl;
                } else {                            // mask channels: sigmoid
                    val = __fdividef(1.f, 1.f + __expf(-val));
                }
                Lds[ocl * 132 + px] = val;
            }
        }
    }
    __syncthreads();   // single barrier; LDS read-only hereafter

    // ---- contiguous copy-out: 48 plane-rows x 128 px, float4 ----
    // thread j4 = it*256+tid: r = j4>>5 (oc row), c4 = j4&31 (float4 col).
    // 32 consecutive threads write 512 contiguous bytes of one plane-row.
#pragma unroll
    for (int it = 0; it < 6; ++it) {
        const int j4 = it * 256 + tid;
        const int r  = j4 >> 5;
        const int c4 = j4 & 31;
        const int oc = m0 + r;
        int g, k, slot;
        if (oc < 2 * DG_ * KK_) {
            g = oc / 18;
            const int rem = oc - g * 18;
            k = rem >> 1;
            slot = rem & 1;
        } else {
            const int c = oc - 2 * DG_ * KK_;
            g = c / 9;
            k = c - g * 9;
            slot = 2;
        }
        const float4 v = *(const float4*)&Lds[r * 132 + c4 * 4];
        float4* dst = (float4*)(omap +
            ((size_t)((b * DG_ * KK_ + g * KK_ + k) * 3 + slot)) * HW_ + y * W_);
        dst[c4] = v;
    }
}

// ---------------------------------------------------------------------------
// Phase A: bilinear gather -> f16 val in [b*HW+pix][r] layout, r = k*64+g*4+c.
// ---------------------------------------------------------------------------
__global__ __launch_bounds__(256) void gather_k(
    const float* __restrict__ x, const float* __restrict__ omap,
    _Float16* __restrict__ valh)
{
    const int tid = threadIdx.x;
    const int gi  = tid & 3;                  // g within quad group
    const int pl  = tid >> 2;                 // 0..63 pixel local
    const int pix = blockIdx.x * 64 + pl;
    const int zy  = blockIdx.y;               // b*36 + gq*9 + k
    const int b   = zy / 36;
    const int rem = zy - b * 36;
    const int gq  = rem / 9;
    const int k   = rem - gq * 9;
    const int g   = gq * 4 + gi;
    const int yp  = pix >> 7;
    const int xp  = pix & (W_ - 1);

    const size_t obase = ((size_t)((b * DG_ + g) * KK_ + k) * 3) * HW_ + pix;
    const float oy = omap[obase];
    const float ox = omap[obase + HW_];
    const float m  = omap[obase + 2 * HW_];

    const float py = (float)(yp + (k / 3) - 1) + oy;
    const float px = (float)(xp + (k % 3) - 1) + ox;
    const float y0f = floorf(py);
    const float x0f = floorf(px);
    const float wy = py - y0f;
    const float wx = px - x0f;
    const int y0 = (int)y0f, x0 = (int)x0f;
    const int y1 = y0 + 1,  x1 = x0 + 1;
    const bool vy0 = ((unsigned)y0 < (unsigned)H_);
    const bool vy1 = ((unsigned)y1 < (unsigned)H_);
    const bool vx0 = ((unsigned)x0 < (unsigned)W_);
    const bool vx1 = ((unsigned)x1 < (unsigned)W_);
    const float w00 = vy0 && vx0 ? (1.f - wy) * (1.f - wx) : 0.f;
    const float w01 = vy0 && vx1 ? (1.f - wy) * wx         : 0.f;
    const float w10 = vy1 && vx0 ? wy * (1.f - wx)         : 0.f;
    const float w11 = vy1 && vx1 ? wy * wx                 : 0.f;
    const int i00 = (vy0 && vx0) ? y0 * W_ + x0 : 0;
    const int i01 = (vy0 && vx1) ? y0 * W_ + x1 : 0;
    const int i10 = (vy1 && vx0) ? y1 * W_ + x0 : 0;
    const int i11 = (vy1 && vx1) ? y1 * W_ + x1 : 0;

    const float* xg = x + (size_t)(b * C_ + g * CG_) * HW_;
    half4 v4;
#pragma unroll
    for (int c = 0; c < CG_; ++c) {
        const float* img = xg + (size_t)c * HW_;
        float v = w00 * img[i00] + w01 * img[i01] + w10 * img[i10] + w11 * img[i11];
        v4[c] = (_Float16)(v * m);
    }
    *(half4*)&valh[((size_t)(b * HW_ + pix)) * R_ + k * 64 + g * 4] = v4;
}

// ---------------------------------------------------------------------------
// Phase B: einsum via f16 MFMA. K split 3 ways; fp32 partials.
// ---------------------------------------------------------------------------
__global__ __launch_bounds__(256) void einsum_mfma_k(
    const _Float16* __restrict__ valh, const _Float16* __restrict__ wkA,
    float* __restrict__ part)
{
    const int tid  = threadIdx.x;
    const int lane = tid & 63;
    const int wv   = tid >> 6;
    const int l15  = lane & 15;
    const int quad = lane >> 4;

    const int pixg0 = blockIdx.x * 128 + wv * 32;   // global pixel (b*HW+pix)
    const int ks    = blockIdx.y;                   // K slice 0..2
    const int s0    = ks * 6;

    floatx4 acc[4][2];
#pragma unroll
    for (int mf = 0; mf < 4; ++mf)
#pragma unroll
        for (int nf = 0; nf < 2; ++nf)
            acc[mf][nf] = (floatx4){0.f, 0.f, 0.f, 0.f};

#pragma unroll
    for (int si = 0; si < 6; ++si) {
        const int s = s0 + si;
        half8 bfr[2];
#pragma unroll
        for (int nf = 0; nf < 2; ++nf)
            bfr[nf] = *(const half8*)&valh[
                (size_t)(pixg0 + nf * 16 + l15) * R_ + s * 32 + quad * 8];
        const _Float16* ap = wkA + (size_t)s * 64 * 32;
#pragma unroll
        for (int mf = 0; mf < 4; ++mf) {
            const half8 afr = *(const half8*)&ap[(mf * 16 + l15) * 32 + quad * 8];
#pragma unroll
            for (int nf = 0; nf < 2; ++nf)
                acc[mf][nf] = __builtin_amdgcn_mfma_f32_16x16x32_f16(
                    afr, bfr[nf], acc[mf][nf], 0, 0, 0);
        }
    }

#pragma unroll
    for (int mf = 0; mf < 4; ++mf) {
#pragma unroll
        for (int nf = 0; nf < 2; ++nf) {
#pragma unroll
            for (int reg = 0; reg < 4; ++reg) {
                const int pixg = pixg0 + nf * 16 + l15;
                const int b    = pixg >> 14;
                const int pix  = pixg & (HW_ - 1);
                const int oc   = mf * 16 + quad * 4 + reg;
                part[(size_t)ks * (B_ * C_ * HW_) +
                     ((size_t)(b * C_ + oc)) * HW_ + pix] = acc[mf][nf][reg];
            }
        }
    }
}

// ---------------------------------------------------------------------------
// Combine the 3 K-slice partials into d_out (float4 vectorized).
// ---------------------------------------------------------------------------
__global__ __launch_bounds__(256) void combine3_k(
    const float4* __restrict__ part, float4* __restrict__ out)
{
    constexpr int N4 = B_ * C_ * HW_ / 4;   // 524288
    const int i = blockIdx.x * 256 + threadIdx.x;
    if (i >= N4) return;
    float4 a = part[i];
    const float4 b = part[i + N4];
    const float4 c = part[i + 2 * N4];
    a.x += b.x + c.x;
    a.y += b.y + c.y;
    a.z += b.z + c.z;
    a.w += b.w + c.w;
    out[i] = a;
}

// ---------------------------------------------------------------------------
extern "C" void kernel_launch(void* const* d_in, const int* in_sizes, int n_in,
                              void* d_out, int out_size, void* d_ws, size_t ws_size,
                              hipStream_t stream)
{
    const float* x    = (const float*)d_in[0];
    const float* ef   = (const float*)d_in[1];
    const float* flow = (const float*)d_in[2];
    const float* w1   = (const float*)d_in[3];
    const float* b1   = (const float*)d_in[4];
    const float* w2   = (const float*)d_in[5];
    const float* b2   = (const float*)d_in[6];
    const float* w3   = (const float*)d_in[7];
    const float* b3   = (const float*)d_in[8];
    const float* wk   = (const float*)d_in[9];
    float* out = (float*)d_out;

    // Workspace (float slots):
    //   om 14,155,776 | valh 9,437,184 | ef_n 2,097,152 | h1n 1,048,576
    //   h2n 1,048,576 | w1A 36,864 | w2A 18,432 | w3A 124,416 | wkA 18,432
    //   [part 6,291,456 if ws permits, else alias om]
    float*    om   = (float*)d_ws;
    _Float16* valh = (_Float16*)(om + (size_t)B_ * OFFC_ * HW_);
    _Float16* ef_n = valh + (size_t)B_ * HW_ * R_;
    _Float16* h1n  = ef_n + (size_t)B_ * HW_ * 128;
    _Float16* h2n  = h1n + (size_t)B_ * HW_ * 64;
    _Float16* w1A  = h2n + (size_t)B_ * HW_ * 64;
    _Float16* w2A  = w1A + 64 * 128 * 9;
    _Float16* w3A  = w2A + 64 * 64 * 9;
    _Float16* wkA  = w3A + OFFC_ * 64 * 9;
    float*    end  = (float*)(wkA + 18 * 64 * 32);
    const size_t need_sep = ((size_t)(end - om) + (size_t)3 * B_ * C_ * HW_) * 4;
    float*    part = (ws_size >= need_sep) ? end : om;  // constant per deployment

    prep_wA_k<64, 128><<<dim3((64 * 128 * 9 + 255) / 256), 256, 0, stream>>>(w1, w1A);
    prep_wA_k<64, 64><<<dim3((64 * 64 * 9 + 255) / 256), 256, 0, stream>>>(w2, w2A);
    prep_wA_k<OFFC_, 64><<<dim3((OFFC_ * 64 * 9 + 255) / 256), 256, 0, stream>>>(w3, w3A);
    prep_wkA_k<<<dim3((18 * 64 * 32 + 255) / 256), 256, 0, stream>>>(wk, wkA);
    nchw2nhwc_f16_k<128><<<dim3(HW_ / 256, B_), 256, 0, stream>>>(ef, ef_n);

    conv12_mfma_k<128><<<dim3(B_ * H_ * 2, 4), 256, 0, stream>>>(ef_n, w1A, b1, h1n);
    conv12_mfma_k<64><<<dim3(B_ * H_ * 2, 4), 256, 0, stream>>>(h1n, w2A, b2, h2n);
    conv3_mfma_k<<<dim3(B_ * H_, 9), 256, 0, stream>>>(h2n, w3A, b3, flow, om);

    gather_k<<<dim3(HW_ / 64, B_ * 4 * KK_), 256, 0, stream>>>(x, om, valh);
    einsum_mfma_k<<<dim3(B_ * HW_ / 128, 3), 256, 0, stream>>>(valh, wkA, part);
    combine3_k<<<dim3((B_ * C_ * HW_ / 4 + 255) / 256), 256, 0, stream>>>((const float4*)part, (float4*)out);
}

// Round 12
// 329.495 us; speedup vs baseline: 1.7094x; 1.0417x over previous
//
#include <hip/hip_runtime.h>
#include <math.h>

// Problem constants (fixed by setup_inputs)
constexpr int B_   = 2;
constexpr int C_   = 64;
constexpr int H_   = 128;
constexpr int W_   = 128;
constexpr int HW_  = H_ * W_;
constexpr int DG_  = 16;   // deformable groups
constexpr int KK_  = 9;    // 3x3 taps
constexpr int CG_  = 4;    // channels per group = C/DG
constexpr int OFFC_ = 3 * KK_ * DG_;  // 432
constexpr int R_   = C_ * KK_;        // 576 reduction length

typedef _Float16 half8 __attribute__((ext_vector_type(8)));  // 8 f16 = 4 VGPR
typedef _Float16 half4 __attribute__((ext_vector_type(4)));  // 8-byte load/store
typedef float floatx4 __attribute__((ext_vector_type(4)));   // MFMA acc

// ---------------------------------------------------------------------------
// Generic MFMA A-operand prep: wA[(t*CH+h)*OC + oc][j] = f16(w[oc][(h*32+j)*9+t])
// ---------------------------------------------------------------------------
template <int OC, int CIN>
__global__ __launch_bounds__(256) void prep_wA_k(
    const float* __restrict__ w, _Float16* __restrict__ wA)
{
    constexpr int CH = CIN / 32;
    const int j = blockIdx.x * 256 + threadIdx.x;   // slab*OC*32 + oc*32 + jj
    if (j >= 9 * CH * OC * 32) return;
    const int slab = j / (OC * 32);
    const int rem  = j - slab * (OC * 32);
    const int oc   = rem >> 5;
    const int jj   = rem & 31;
    const int t    = slab / CH;
    const int h    = slab - t * CH;
    const int ic   = h * 32 + jj;
    wA[j] = (_Float16)w[(size_t)oc * (CIN * 9) + ic * 9 + t];
}

// ---------------------------------------------------------------------------
// Einsum A-operand prep: r = k*64 + gc (gc = g*4+c).  18 slabs of 32.
// ---------------------------------------------------------------------------
__global__ __launch_bounds__(256) void prep_wkA_k(
    const float* __restrict__ wk, _Float16* __restrict__ wkA)
{
    const int j = blockIdx.x * 256 + threadIdx.x;   // s*2048 + oc*32 + jj
    if (j >= 18 * 64 * 32) return;
    const int s   = j >> 11;
    const int rem = j & 2047;
    const int oc  = rem >> 5;
    const int jj  = rem & 31;
    const int k   = s >> 1;
    const int gc  = (s & 1) * 32 + jj;
    wkA[j] = (_Float16)wk[(size_t)oc * R_ + gc * 9 + k];
}

// ---------------------------------------------------------------------------
// NCHW fp32 -> NHWC f16.
// ---------------------------------------------------------------------------
template <int CC>
__global__ __launch_bounds__(256) void nchw2nhwc_f16_k(
    const float* __restrict__ in, _Float16* __restrict__ outh)
{
    const int pix = blockIdx.x * 256 + threadIdx.x;
    const int b   = blockIdx.y;
    const float* ib = in + (size_t)b * CC * HW_ + pix;
    _Float16* ob = outh + ((size_t)b * HW_ + pix) * CC;
#pragma unroll
    for (int c0 = 0; c0 < CC; c0 += 8) {
        half8 v;
#pragma unroll
        for (int j = 0; j < 8; ++j)
            v[j] = (_Float16)ib[(size_t)(c0 + j) * HW_];
        *(half8*)&ob[c0] = v;
    }
}

// ---------------------------------------------------------------------------
// Conv1/conv2 (CIN -> 64) via f16 MFMA, no LDS, no barriers, fused leaky.
// ---------------------------------------------------------------------------
template <int CIN>
__global__ __launch_bounds__(256) void conv12_mfma_k(
    const _Float16* __restrict__ inn, const _Float16* __restrict__ wA,
    const float* __restrict__ bias, _Float16* __restrict__ outn)
{
    constexpr int CH = CIN / 32;
    const int tid  = threadIdx.x;
    const int lane = tid & 63;
    const int wv   = tid >> 6;
    const int l15  = lane & 15;
    const int quad = lane >> 4;

    const int zx   = blockIdx.x;          // (b*H + y)*2 + half64
    const int row  = zx >> 1;
    const int b    = row >> 7;
    const int y    = row & 127;
    const int px0  = (zx & 1) * 64 + wv * 16;
    const int oct  = blockIdx.y;          // oc tile (16 chans)

    floatx4 acc = (floatx4){0.f, 0.f, 0.f, 0.f};
    const _Float16* inb = inn + (size_t)b * HW_ * CIN;

    for (int t = 0; t < 9; ++t) {
        const int dy = t / 3, dx = t % 3;
        const int yy = y + dy - 1;
        const int xx = px0 + l15 + dx - 1;
        const bool v = ((unsigned)yy < (unsigned)H_) && ((unsigned)xx < (unsigned)W_);
        const _Float16* bp = inb + ((size_t)yy * W_ + xx) * CIN + quad * 8;
        const _Float16* ap = wA + ((size_t)(t * CH) * 64 + oct * 16 + l15) * 32 + quad * 8;
#pragma unroll
        for (int h = 0; h < CH; ++h) {
            half8 bfr = (half8){0, 0, 0, 0, 0, 0, 0, 0};
            if (v) bfr = *(const half8*)&bp[h * 32];
            const half8 afr = *(const half8*)&ap[(size_t)h * 64 * 32];
            acc = __builtin_amdgcn_mfma_f32_16x16x32_f16(afr, bfr, acc, 0, 0, 0);
        }
    }

    const int pix = y * W_ + px0 + l15;
    half4 v4;
#pragma unroll
    for (int reg = 0; reg < 4; ++reg) {
        float r = acc[reg] + bias[oct * 16 + quad * 4 + reg];
        r = (r >= 0.f) ? r : 0.1f * r;
        v4[reg] = (_Float16)r;
    }
    *(half4*)&outn[((size_t)b * HW_ + pix) * 64 + oct * 16 + quad * 4] = v4;
}

// ---------------------------------------------------------------------------
// Conv3 via f16 MFMA implicit GEMM + LDS-staged epilogue, f16 omap output
// (halves the dominant write stream: 56.6 -> 28.3 MB).
// Tile: wave = 32 px (nf=2) x 48 oc (mf=3); grid (B*H, 9) = 2304 blocks.
// LDS: 48 x 132 floats = 25.3 KB, write-once -> single barrier -> read-only.
// ---------------------------------------------------------------------------
__global__ __launch_bounds__(256) void conv3_mfma_k(
    const _Float16* __restrict__ h2n, const _Float16* __restrict__ w3A,
    const float* __restrict__ bias, const float* __restrict__ flow,
    _Float16* __restrict__ omh)
{
    __shared__ __align__(16) float Lds[48 * 132];

    const int tid  = threadIdx.x;
    const int lane = tid & 63;
    const int wv   = tid >> 6;       // wave id 0..3
    const int l15  = lane & 15;
    const int quad = lane >> 4;

    const int row = blockIdx.x;      // b*128 + y
    const int b   = row >> 7;
    const int y   = row & 127;
    const int m0  = blockIdx.y * 48; // oc tile base
    const int px0 = wv * 32;

    floatx4 acc[3][2];
#pragma unroll
    for (int mf = 0; mf < 3; ++mf)
#pragma unroll
        for (int nf = 0; nf < 2; ++nf)
            acc[mf][nf] = (floatx4){0.f, 0.f, 0.f, 0.f};

    const _Float16* h2b = h2n + (size_t)b * HW_ * C_;

    for (int t = 0; t < 9; ++t) {
        const int dy = t / 3, dx = t % 3;
        const int yy = y + dy - 1;
        const bool vy = ((unsigned)yy < (unsigned)H_);
#pragma unroll
        for (int h = 0; h < 2; ++h) {        // two 32-ic halves of K
            half8 bfr[2];
#pragma unroll
            for (int nf = 0; nf < 2; ++nf) {
                const int xx = px0 + nf * 16 + l15 + dx - 1;
                half8 v = (half8){0, 0, 0, 0, 0, 0, 0, 0};
                if (vy && (unsigned)xx < (unsigned)W_)
                    v = *(const half8*)&h2b[((size_t)yy * W_ + xx) * C_ + h * 32 + quad * 8];
                bfr[nf] = v;
            }
            const _Float16* wbase = w3A + ((size_t)(t * 2 + h) * OFFC_ + m0) * 32;
#pragma unroll
            for (int mf = 0; mf < 3; ++mf) {
                const half8 afr = *(const half8*)&wbase[(mf * 16 + l15) * 32 + quad * 8];
#pragma unroll
                for (int nf = 0; nf < 2; ++nf)
                    acc[mf][nf] = __builtin_amdgcn_mfma_f32_16x16x32_f16(
                        afr, bfr[nf], acc[mf][nf], 0, 0, 0);
            }
        }
    }

    // ---- transform + stage to LDS (each thread writes 24 unique slots) ----
#pragma unroll
    for (int mf = 0; mf < 3; ++mf) {
#pragma unroll
        for (int nf = 0; nf < 2; ++nf) {
#pragma unroll
            for (int reg = 0; reg < 4; ++reg) {
                const int ocl = mf * 16 + quad * 4 + reg;   // 0..47
                const int oc  = m0 + ocl;
                const int px  = px0 + nf * 16 + l15;
                float val = acc[mf][nf][reg] + bias[oc];
                if (oc < 2 * DG_ * KK_) {          // offset channels
                    const int slot = oc & 1;        // 0 = y, 1 = x
                    const float fl = flow[(size_t)(b * 2 + (1 - slot)) * HW_ + y * W_ + px];
                    const float e = __expf(2.f * val);      // tanh via exp
                    val = 10.f * (1.f - __fdividef(2.f, e + 1.f)) + fl;
                } else {                            // mask channels: sigmoid
                    val = __fdividef(1.f, 1.f + __expf(-val));
                }
                Lds[ocl * 132 + px] = val;
            }
        }
    }
    __syncthreads();   // single barrier; LDS read-only hereafter

    // ---- contiguous f16 copy-out: 48 plane-rows x 128 px ----
    // thread j4: r = j4>>5 (oc row), c4 = j4&31 (4-px group). 32 consecutive
    // threads cover one plane-row = 256 contiguous bytes.
#pragma unroll
    for (int it = 0; it < 6; ++it) {
        const int j4 = it * 256 + tid;
        const int r  = j4 >> 5;
        const int c4 = j4 & 31;
        const int oc = m0 + r;
        int g, k, slot;
        if (oc < 2 * DG_ * KK_) {
            g = oc / 18;
            const int rem = oc - g * 18;
            k = rem >> 1;
            slot = rem & 1;
        } else {
            const int c = oc - 2 * DG_ * KK_;
            g = c / 9;
            k = c - g * 9;
            slot = 2;
        }
        half4 hv;
#pragma unroll
        for (int j = 0; j < 4; ++j)
            hv[j] = (_Float16)Lds[r * 132 + c4 * 4 + j];
        *(half4*)&omh[((size_t)((b * DG_ * KK_ + g * KK_ + k) * 3 + slot)) * HW_
                      + y * W_ + c4 * 4] = hv;
    }
}

// ---------------------------------------------------------------------------
// Phase A: bilinear gather -> f16 val in [b*HW+pix][r], r = k*64+g*4+c.
// x pre-converted to NHWC f16: the 4 group-channels are one contiguous
// half4 per corner -> 4 loads/thread instead of 16.
// ---------------------------------------------------------------------------
__global__ __launch_bounds__(256) void gather_k(
    const _Float16* __restrict__ xn, const _Float16* __restrict__ omh,
    _Float16* __restrict__ valh)
{
    const int tid = threadIdx.x;
    const int gi  = tid & 3;                  // g within quad group
    const int pl  = tid >> 2;                 // 0..63 pixel local
    const int pix = blockIdx.x * 64 + pl;
    const int zy  = blockIdx.y;               // b*36 + gq*9 + k
    const int b   = zy / 36;
    const int rem = zy - b * 36;
    const int gq  = rem / 9;
    const int k   = rem - gq * 9;
    const int g   = gq * 4 + gi;
    const int yp  = pix >> 7;
    const int xp  = pix & (W_ - 1);

    const size_t obase = ((size_t)((b * DG_ + g) * KK_ + k) * 3) * HW_ + pix;
    const float oy = (float)omh[obase];
    const float ox = (float)omh[obase + HW_];
    const float m  = (float)omh[obase + 2 * HW_];

    const float py = (float)(yp + (k / 3) - 1) + oy;
    const float px = (float)(xp + (k % 3) - 1) + ox;
    const float y0f = floorf(py);
    const float x0f = floorf(px);
    const float wy = py - y0f;
    const float wx = px - x0f;
    const int y0 = (int)y0f, x0 = (int)x0f;
    const int y1 = y0 + 1,  x1 = x0 + 1;
    const bool vy0 = ((unsigned)y0 < (unsigned)H_);
    const bool vy1 = ((unsigned)y1 < (unsigned)H_);
    const bool vx0 = ((unsigned)x0 < (unsigned)W_);
    const bool vx1 = ((unsigned)x1 < (unsigned)W_);
    const float w00 = vy0 && vx0 ? (1.f - wy) * (1.f - wx) : 0.f;
    const float w01 = vy0 && vx1 ? (1.f - wy) * wx         : 0.f;
    const float w10 = vy1 && vx0 ? wy * (1.f - wx)         : 0.f;
    const float w11 = vy1 && vx1 ? wy * wx                 : 0.f;
    const int i00 = (vy0 && vx0) ? y0 * W_ + x0 : 0;
    const int i01 = (vy0 && vx1) ? y0 * W_ + x1 : 0;
    const int i10 = (vy1 && vx0) ? y1 * W_ + x0 : 0;
    const int i11 = (vy1 && vx1) ? y1 * W_ + x1 : 0;

    const _Float16* xb = xn + (size_t)b * HW_ * C_ + g * CG_;
    const half4 p00 = *(const half4*)&xb[(size_t)i00 * C_];
    const half4 p01 = *(const half4*)&xb[(size_t)i01 * C_];
    const half4 p10 = *(const half4*)&xb[(size_t)i10 * C_];
    const half4 p11 = *(const half4*)&xb[(size_t)i11 * C_];

    half4 v4;
#pragma unroll
    for (int c = 0; c < CG_; ++c) {
        float v = w00 * (float)p00[c] + w01 * (float)p01[c]
                + w10 * (float)p10[c] + w11 * (float)p11[c];
        v4[c] = (_Float16)(v * m);
    }
    *(half4*)&valh[((size_t)(b * HW_ + pix)) * R_ + k * 64 + g * 4] = v4;
}

// ---------------------------------------------------------------------------
// Phase B: einsum via f16 MFMA. K split 3 ways; fp32 partials.
// ---------------------------------------------------------------------------
__global__ __launch_bounds__(256) void einsum_mfma_k(
    const _Float16* __restrict__ valh, const _Float16* __restrict__ wkA,
    float* __restrict__ part)
{
    const int tid  = threadIdx.x;
    const int lane = tid & 63;
    const int wv   = tid >> 6;
    const int l15  = lane & 15;
    const int quad = lane >> 4;

    const int pixg0 = blockIdx.x * 128 + wv * 32;   // global pixel (b*HW+pix)
    const int ks    = blockIdx.y;                   // K slice 0..2
    const int s0    = ks * 6;

    floatx4 acc[4][2];
#pragma unroll
    for (int mf = 0; mf < 4; ++mf)
#pragma unroll
        for (int nf = 0; nf < 2; ++nf)
            acc[mf][nf] = (floatx4){0.f, 0.f, 0.f, 0.f};

#pragma unroll
    for (int si = 0; si < 6; ++si) {
        const int s = s0 + si;
        half8 bfr[2];
#pragma unroll
        for (int nf = 0; nf < 2; ++nf)
            bfr[nf] = *(const half8*)&valh[
                (size_t)(pixg0 + nf * 16 + l15) * R_ + s * 32 + quad * 8];
        const _Float16* ap = wkA + (size_t)s * 64 * 32;
#pragma unroll
        for (int mf = 0; mf < 4; ++mf) {
            const half8 afr = *(const half8*)&ap[(mf * 16 + l15) * 32 + quad * 8];
#pragma unroll
            for (int nf = 0; nf < 2; ++nf)
                acc[mf][nf] = __builtin_amdgcn_mfma_f32_16x16x32_f16(
                    afr, bfr[nf], acc[mf][nf], 0, 0, 0);
        }
    }

#pragma unroll
    for (int mf = 0; mf < 4; ++mf) {
#pragma unroll
        for (int nf = 0; nf < 2; ++nf) {
#pragma unroll
            for (int reg = 0; reg < 4; ++reg) {
                const int pixg = pixg0 + nf * 16 + l15;
                const int b    = pixg >> 14;
                const int pix  = pixg & (HW_ - 1);
                const int oc   = mf * 16 + quad * 4 + reg;
                part[(size_t)ks * (B_ * C_ * HW_) +
                     ((size_t)(b * C_ + oc)) * HW_ + pix] = acc[mf][nf][reg];
            }
        }
    }
}

// ---------------------------------------------------------------------------
// Combine the 3 K-slice partials into d_out (float4 vectorized).
// ---------------------------------------------------------------------------
__global__ __launch_bounds__(256) void combine3_k(
    const float4* __restrict__ part, float4* __restrict__ out)
{
    constexpr int N4 = B_ * C_ * HW_ / 4;   // 524288
    const int i = blockIdx.x * 256 + threadIdx.x;
    if (i >= N4) return;
    float4 a = part[i];
    const float4 b = part[i + N4];
    const float4 c = part[i + 2 * N4];
    a.x += b.x + c.x;
    a.y += b.y + c.y;
    a.z += b.z + c.z;
    a.w += b.w + c.w;
    out[i] = a;
}

// ---------------------------------------------------------------------------
extern "C" void kernel_launch(void* const* d_in, const int* in_sizes, int n_in,
                              void* d_out, int out_size, void* d_ws, size_t ws_size,
                              hipStream_t stream)
{
    const float* x    = (const float*)d_in[0];
    const float* ef   = (const float*)d_in[1];
    const float* flow = (const float*)d_in[2];
    const float* w1   = (const float*)d_in[3];
    const float* b1   = (const float*)d_in[4];
    const float* w2   = (const float*)d_in[5];
    const float* b2   = (const float*)d_in[6];
    const float* w3   = (const float*)d_in[7];
    const float* b3   = (const float*)d_in[8];
    const float* wk   = (const float*)d_in[9];
    float* out = (float*)d_out;

    // Workspace (float slots):
    //   omh 7,077,888 (14.2M halves) | valh 9,437,184 | ef_n 2,097,152
    //   xn 1,048,576 | h1n 1,048,576 | h2n 1,048,576
    //   w1A 36,864 | w2A 18,432 | w3A 124,416 | wkA 18,432
    //   [part 6,291,456 if ws permits, else alias omh (dead after gather)]
    _Float16* omh  = (_Float16*)d_ws;
    _Float16* valh = omh + (size_t)B_ * OFFC_ * HW_;
    _Float16* ef_n = valh + (size_t)B_ * HW_ * R_;
    _Float16* xn   = ef_n + (size_t)B_ * HW_ * 128;
    _Float16* h1n  = xn + (size_t)B_ * HW_ * 64;
    _Float16* h2n  = h1n + (size_t)B_ * HW_ * 64;
    _Float16* w1A  = h2n + (size_t)B_ * HW_ * 64;
    _Float16* w2A  = w1A + 64 * 128 * 9;
    _Float16* w3A  = w2A + 64 * 64 * 9;
    _Float16* wkA  = w3A + OFFC_ * 64 * 9;
    float*    end  = (float*)(wkA + 18 * 64 * 32);
    const size_t need_sep =
        ((char*)end - (char*)d_ws) + (size_t)3 * B_ * C_ * HW_ * 4;
    float*    part = (ws_size >= need_sep) ? end : (float*)omh;  // constant per deployment

    prep_wA_k<64, 128><<<dim3((64 * 128 * 9 + 255) / 256), 256, 0, stream>>>(w1, w1A);
    prep_wA_k<64, 64><<<dim3((64 * 64 * 9 + 255) / 256), 256, 0, stream>>>(w2, w2A);
    prep_wA_k<OFFC_, 64><<<dim3((OFFC_ * 64 * 9 + 255) / 256), 256, 0, stream>>>(w3, w3A);
    prep_wkA_k<<<dim3((18 * 64 * 32 + 255) / 256), 256, 0, stream>>>(wk, wkA);
    nchw2nhwc_f16_k<128><<<dim3(HW_ / 256, B_), 256, 0, stream>>>(ef, ef_n);
    nchw2nhwc_f16_k<64><<<dim3(HW_ / 256, B_), 256, 0, stream>>>(x, xn);

    conv12_mfma_k<128><<<dim3(B_ * H_ * 2, 4), 256, 0, stream>>>(ef_n, w1A, b1, h1n);
    conv12_mfma_k<64><<<dim3(B_ * H_ * 2, 4), 256, 0, stream>>>(h1n, w2A, b2, h2n);
    conv3_mfma_k<<<dim3(B_ * H_, 9), 256, 0, stream>>>(h2n, w3A, b3, flow, omh);

    gather_k<<<dim3(HW_ / 64, B_ * 4 * KK_), 256, 0, stream>>>(xn, omh, valh);
    einsum_mfma_k<<<dim3(B_ * HW_ / 128, 3), 256, 0, stream>>>(valh, wkA, part);
    combine3_k<<<dim3((B_ * C_ * HW_ / 4 + 255) / 256), 256, 0, stream>>>((const float4*)part, (float4*)out);
}

// Round 13
// 291.834 us; speedup vs baseline: 1.9300x; 1.1291x over previous
//
#include <hip/hip_runtime.h>
#include <math.h>

// Problem constants (fixed by setup_inputs)
constexpr int B_   = 2;
constexpr int C_   = 64;
constexpr int H_   = 128;
constexpr int W_   = 128;
constexpr int HW_  = H_ * W_;
constexpr int DG_  = 16;   // deformable groups
constexpr int KK_  = 9;    // 3x3 taps
constexpr int CG_  = 4;    // channels per group = C/DG
constexpr int OFFC_ = 3 * KK_ * DG_;  // 432
constexpr int R_   = C_ * KK_;        // 576 reduction length

typedef _Float16 half8 __attribute__((ext_vector_type(8)));  // 8 f16 = 4 VGPR
typedef _Float16 half4 __attribute__((ext_vector_type(4)));  // 8-byte load/store
typedef float floatx4 __attribute__((ext_vector_type(4)));   // MFMA acc

// ---------------------------------------------------------------------------
// Generic MFMA A-operand prep: wA[(t*CH+h)*OC + oc][j] = f16(w[oc][(h*32+j)*9+t])
// ---------------------------------------------------------------------------
template <int OC, int CIN>
__global__ __launch_bounds__(256) void prep_wA_k(
    const float* __restrict__ w, _Float16* __restrict__ wA)
{
    constexpr int CH = CIN / 32;
    const int j = blockIdx.x * 256 + threadIdx.x;   // slab*OC*32 + oc*32 + jj
    if (j >= 9 * CH * OC * 32) return;
    const int slab = j / (OC * 32);
    const int rem  = j - slab * (OC * 32);
    const int oc   = rem >> 5;
    const int jj   = rem & 31;
    const int t    = slab / CH;
    const int h    = slab - t * CH;
    const int ic   = h * 32 + jj;
    wA[j] = (_Float16)w[(size_t)oc * (CIN * 9) + ic * 9 + t];
}

// ---------------------------------------------------------------------------
// Einsum A-operand prep: r = k*64 + gc (gc = g*4+c).  18 slabs of 32.
// ---------------------------------------------------------------------------
__global__ __launch_bounds__(256) void prep_wkA_k(
    const float* __restrict__ wk, _Float16* __restrict__ wkA)
{
    const int j = blockIdx.x * 256 + threadIdx.x;   // s*2048 + oc*32 + jj
    if (j >= 18 * 64 * 32) return;
    const int s   = j >> 11;
    const int rem = j & 2047;
    const int oc  = rem >> 5;
    const int jj  = rem & 31;
    const int k   = s >> 1;
    const int gc  = (s & 1) * 32 + jj;
    wkA[j] = (_Float16)wk[(size_t)oc * R_ + gc * 9 + k];
}

// ---------------------------------------------------------------------------
// NCHW fp32 -> slab-split NHWC f16: out[(c/32)*B + b][pix][32].
// A pixel record = 64 B = one MFMA K-slab -> contiguous B-fragment loads.
// ---------------------------------------------------------------------------
template <int CC>
__global__ __launch_bounds__(256) void nchw2slab_f16_k(
    const float* __restrict__ in, _Float16* __restrict__ outh)
{
    const int pix = blockIdx.x * 256 + threadIdx.x;
    const int b   = blockIdx.y;
    const float* ib = in + (size_t)b * CC * HW_ + pix;
#pragma unroll
    for (int c0 = 0; c0 < CC; c0 += 8) {
        half8 v;
#pragma unroll
        for (int j = 0; j < 8; ++j)
            v[j] = (_Float16)ib[(size_t)(c0 + j) * HW_];
        const int slab = c0 >> 5;
        *(half8*)&outh[((size_t)(slab * B_ + b) * HW_ + pix) * 32 + (c0 & 31)] = v;
    }
}

// ---------------------------------------------------------------------------
// NCHW fp32 -> plain NHWC f16 (for gather's x: half4 at g*4 within 64-rec).
// ---------------------------------------------------------------------------
template <int CC>
__global__ __launch_bounds__(256) void nchw2nhwc_f16_k(
    const float* __restrict__ in, _Float16* __restrict__ outh)
{
    const int pix = blockIdx.x * 256 + threadIdx.x;
    const int b   = blockIdx.y;
    const float* ib = in + (size_t)b * CC * HW_ + pix;
    _Float16* ob = outh + ((size_t)b * HW_ + pix) * CC;
#pragma unroll
    for (int c0 = 0; c0 < CC; c0 += 8) {
        half8 v;
#pragma unroll
        for (int j = 0; j < 8; ++j)
            v[j] = (_Float16)ib[(size_t)(c0 + j) * HW_];
        *(half8*)&ob[c0] = v;
    }
}

// ---------------------------------------------------------------------------
// Conv1/conv2 (CIN -> 64) via f16 MFMA, no LDS, no barriers, fused leaky.
// Slab-split input AND output: B-fragment loads are 1-KB contiguous.
// ---------------------------------------------------------------------------
template <int CIN>
__global__ __launch_bounds__(256) void conv12_mfma_k(
    const _Float16* __restrict__ inn, const _Float16* __restrict__ wA,
    const float* __restrict__ bias, _Float16* __restrict__ outn)
{
    constexpr int CH = CIN / 32;
    const int tid  = threadIdx.x;
    const int lane = tid & 63;
    const int wv   = tid >> 6;
    const int l15  = lane & 15;
    const int quad = lane >> 4;

    const int zx   = blockIdx.x;          // (b*H + y)*2 + half64
    const int row  = zx >> 1;
    const int b    = row >> 7;
    const int y    = row & 127;
    const int px0  = (zx & 1) * 64 + wv * 16;
    const int oct  = blockIdx.y;          // oc tile (16 chans)

    floatx4 acc = (floatx4){0.f, 0.f, 0.f, 0.f};

    for (int t = 0; t < 9; ++t) {
        const int dy = t / 3, dx = t % 3;
        const int yy = y + dy - 1;
        const int xx = px0 + l15 + dx - 1;
        const bool v = ((unsigned)yy < (unsigned)H_) && ((unsigned)xx < (unsigned)W_);
        const _Float16* ap = wA + ((size_t)(t * CH) * 64 + oct * 16 + l15) * 32 + quad * 8;
#pragma unroll
        for (int h = 0; h < CH; ++h) {
            half8 bfr = (half8){0, 0, 0, 0, 0, 0, 0, 0};
            if (v) bfr = *(const half8*)&inn[
                ((size_t)(h * B_ + b) * HW_ + (size_t)yy * W_ + xx) * 32 + quad * 8];
            const half8 afr = *(const half8*)&ap[(size_t)h * 64 * 32];
            acc = __builtin_amdgcn_mfma_f32_16x16x32_f16(afr, bfr, acc, 0, 0, 0);
        }
    }

    // epilogue: leaky ReLU, slab-split f16 store (8 B/lane)
    const int pix = y * W_ + px0 + l15;
    const int oc4 = oct * 16 + quad * 4;        // first of 4 output chans
    half4 v4;
#pragma unroll
    for (int reg = 0; reg < 4; ++reg) {
        float r = acc[reg] + bias[oc4 + reg];
        r = (r >= 0.f) ? r : 0.1f * r;
        v4[reg] = (_Float16)r;
    }
    *(half4*)&outn[((size_t)((oc4 >> 5) * B_ + b) * HW_ + pix) * 32 + (oc4 & 31)] = v4;
}

// ---------------------------------------------------------------------------
// Conv3 via f16 MFMA implicit GEMM + LDS-staged epilogue, f16 omap output.
// Slab-split input: each B-fragment load = 1-KB contiguous (16 x 64-B recs).
// Tile: wave = 32 px (nf=2) x 48 oc (mf=3); grid (B*H, 9) = 2304 blocks.
// LDS: 48 x 132 floats = 25.3 KB, write-once -> single barrier -> read-only.
// ---------------------------------------------------------------------------
__global__ __launch_bounds__(256) void conv3_mfma_k(
    const _Float16* __restrict__ h2s, const _Float16* __restrict__ w3A,
    const float* __restrict__ bias, const float* __restrict__ flow,
    _Float16* __restrict__ omh)
{
    __shared__ __align__(16) float Lds[48 * 132];

    const int tid  = threadIdx.x;
    const int lane = tid & 63;
    const int wv   = tid >> 6;       // wave id 0..3
    const int l15  = lane & 15;
    const int quad = lane >> 4;

    const int row = blockIdx.x;      // b*128 + y
    const int b   = row >> 7;
    const int y   = row & 127;
    const int m0  = blockIdx.y * 48; // oc tile base
    const int px0 = wv * 32;

    floatx4 acc[3][2];
#pragma unroll
    for (int mf = 0; mf < 3; ++mf)
#pragma unroll
        for (int nf = 0; nf < 2; ++nf)
            acc[mf][nf] = (floatx4){0.f, 0.f, 0.f, 0.f};

    for (int t = 0; t < 9; ++t) {
        const int dy = t / 3, dx = t % 3;
        const int yy = y + dy - 1;
        const bool vy = ((unsigned)yy < (unsigned)H_);
#pragma unroll
        for (int h = 0; h < 2; ++h) {        // two 32-ic slabs of K
            half8 bfr[2];
#pragma unroll
            for (int nf = 0; nf < 2; ++nf) {
                const int xx = px0 + nf * 16 + l15 + dx - 1;
                half8 v = (half8){0, 0, 0, 0, 0, 0, 0, 0};
                if (vy && (unsigned)xx < (unsigned)W_)
                    v = *(const half8*)&h2s[
                        ((size_t)(h * B_ + b) * HW_ + (size_t)yy * W_ + xx) * 32 + quad * 8];
                bfr[nf] = v;
            }
            const _Float16* wbase = w3A + ((size_t)(t * 2 + h) * OFFC_ + m0) * 32;
#pragma unroll
            for (int mf = 0; mf < 3; ++mf) {
                const half8 afr = *(const half8*)&wbase[(mf * 16 + l15) * 32 + quad * 8];
#pragma unroll
                for (int nf = 0; nf < 2; ++nf)
                    acc[mf][nf] = __builtin_amdgcn_mfma_f32_16x16x32_f16(
                        afr, bfr[nf], acc[mf][nf], 0, 0, 0);
            }
        }
    }

    // ---- transform + stage to LDS (each thread writes 24 unique slots) ----
#pragma unroll
    for (int mf = 0; mf < 3; ++mf) {
#pragma unroll
        for (int nf = 0; nf < 2; ++nf) {
#pragma unroll
            for (int reg = 0; reg < 4; ++reg) {
                const int ocl = mf * 16 + quad * 4 + reg;   // 0..47
                const int oc  = m0 + ocl;
                const int px  = px0 + nf * 16 + l15;
                float val = acc[mf][nf][reg] + bias[oc];
                if (oc < 2 * DG_ * KK_) {          // offset channels
                    const int slot = oc & 1;        // 0 = y, 1 = x
                    const float fl = flow[(size_t)(b * 2 + (1 - slot)) * HW_ + y * W_ + px];
                    const float e = __expf(2.f * val);      // tanh via exp
                    val = 10.f * (1.f - __fdividef(2.f, e + 1.f)) + fl;
                } else {                            // mask channels: sigmoid
                    val = __fdividef(1.f, 1.f + __expf(-val));
                }
                Lds[ocl * 132 + px] = val;
            }
        }
    }
    __syncthreads();   // single barrier; LDS read-only hereafter

    // ---- contiguous f16 copy-out: 48 plane-rows x 128 px ----
#pragma unroll
    for (int it = 0; it < 6; ++it) {
        const int j4 = it * 256 + tid;
        const int r  = j4 >> 5;
        const int c4 = j4 & 31;
        const int oc = m0 + r;
        int g, k, slot;
        if (oc < 2 * DG_ * KK_) {
            g = oc / 18;
            const int rem = oc - g * 18;
            k = rem >> 1;
            slot = rem & 1;
        } else {
            const int c = oc - 2 * DG_ * KK_;
            g = c / 9;
            k = c - g * 9;
            slot = 2;
        }
        half4 hv;
#pragma unroll
        for (int j = 0; j < 4; ++j)
            hv[j] = (_Float16)Lds[r * 132 + c4 * 4 + j];
        *(half4*)&omh[((size_t)((b * DG_ * KK_ + g * KK_ + k) * 3 + slot)) * HW_
                      + y * W_ + c4 * 4] = hv;
    }
}

// ---------------------------------------------------------------------------
// Phase A: bilinear gather -> f16 val in [b*HW+pix][r], r = k*64+g*4+c.
// ---------------------------------------------------------------------------
__global__ __launch_bounds__(256) void gather_k(
    const _Float16* __restrict__ xn, const _Float16* __restrict__ omh,
    _Float16* __restrict__ valh)
{
    const int tid = threadIdx.x;
    const int gi  = tid & 3;                  // g within quad group
    const int pl  = tid >> 2;                 // 0..63 pixel local
    const int pix = blockIdx.x * 64 + pl;
    const int zy  = blockIdx.y;               // b*36 + gq*9 + k
    const int b   = zy / 36;
    const int rem = zy - b * 36;
    const int gq  = rem / 9;
    const int k   = rem - gq * 9;
    const int g   = gq * 4 + gi;
    const int yp  = pix >> 7;
    const int xp  = pix & (W_ - 1);

    const size_t obase = ((size_t)((b * DG_ + g) * KK_ + k) * 3) * HW_ + pix;
    const float oy = (float)omh[obase];
    const float ox = (float)omh[obase + HW_];
    const float m  = (float)omh[obase + 2 * HW_];

    const float py = (float)(yp + (k / 3) - 1) + oy;
    const float px = (float)(xp + (k % 3) - 1) + ox;
    const float y0f = floorf(py);
    const float x0f = floorf(px);
    const float wy = py - y0f;
    const float wx = px - x0f;
    const int y0 = (int)y0f, x0 = (int)x0f;
    const int y1 = y0 + 1,  x1 = x0 + 1;
    const bool vy0 = ((unsigned)y0 < (unsigned)H_);
    const bool vy1 = ((unsigned)y1 < (unsigned)H_);
    const bool vx0 = ((unsigned)x0 < (unsigned)W_);
    const bool vx1 = ((unsigned)x1 < (unsigned)W_);
    const float w00 = vy0 && vx0 ? (1.f - wy) * (1.f - wx) : 0.f;
    const float w01 = vy0 && vx1 ? (1.f - wy) * wx         : 0.f;
    const float w10 = vy1 && vx0 ? wy * (1.f - wx)         : 0.f;
    const float w11 = vy1 && vx1 ? wy * wx                 : 0.f;
    const int i00 = (vy0 && vx0) ? y0 * W_ + x0 : 0;
    const int i01 = (vy0 && vx1) ? y0 * W_ + x1 : 0;
    const int i10 = (vy1 && vx0) ? y1 * W_ + x0 : 0;
    const int i11 = (vy1 && vx1) ? y1 * W_ + x1 : 0;

    const _Float16* xb = xn + (size_t)b * HW_ * C_ + g * CG_;
    const half4 p00 = *(const half4*)&xb[(size_t)i00 * C_];
    const half4 p01 = *(const half4*)&xb[(size_t)i01 * C_];
    const half4 p10 = *(const half4*)&xb[(size_t)i10 * C_];
    const half4 p11 = *(const half4*)&xb[(size_t)i11 * C_];

    half4 v4;
#pragma unroll
    for (int c = 0; c < CG_; ++c) {
        float v = w00 * (float)p00[c] + w01 * (float)p01[c]
                + w10 * (float)p10[c] + w11 * (float)p11[c];
        v4[c] = (_Float16)(v * m);
    }
    *(half4*)&valh[((size_t)(b * HW_ + pix)) * R_ + k * 64 + g * 4] = v4;
}

// ---------------------------------------------------------------------------
// Phase B: einsum via f16 MFMA. K split 3 ways; fp32 partials.
// ---------------------------------------------------------------------------
__global__ __launch_bounds__(256) void einsum_mfma_k(
    const _Float16* __restrict__ valh, const _Float16* __restrict__ wkA,
    float* __restrict__ part)
{
    const int tid  = threadIdx.x;
    const int lane = tid & 63;
    const int wv   = tid >> 6;
    const int l15  = lane & 15;
    const int quad = lane >> 4;

    const int pixg0 = blockIdx.x * 128 + wv * 32;   // global pixel (b*HW+pix)
    const int ks    = blockIdx.y;                   // K slice 0..2
    const int s0    = ks * 6;

    floatx4 acc[4][2];
#pragma unroll
    for (int mf = 0; mf < 4; ++mf)
#pragma unroll
        for (int nf = 0; nf < 2; ++nf)
            acc[mf][nf] = (floatx4){0.f, 0.f, 0.f, 0.f};

#pragma unroll
    for (int si = 0; si < 6; ++si) {
        const int s = s0 + si;
        half8 bfr[2];
#pragma unroll
        for (int nf = 0; nf < 2; ++nf)
            bfr[nf] = *(const half8*)&valh[
                (size_t)(pixg0 + nf * 16 + l15) * R_ + s * 32 + quad * 8];
        const _Float16* ap = wkA + (size_t)s * 64 * 32;
#pragma unroll
        for (int mf = 0; mf < 4; ++mf) {
            const half8 afr = *(const half8*)&ap[(mf * 16 + l15) * 32 + quad * 8];
#pragma unroll
            for (int nf = 0; nf < 2; ++nf)
                acc[mf][nf] = __builtin_amdgcn_mfma_f32_16x16x32_f16(
                    afr, bfr[nf], acc[mf][nf], 0, 0, 0);
        }
    }

#pragma unroll
    for (int mf = 0; mf < 4; ++mf) {
#pragma unroll
        for (int nf = 0; nf < 2; ++nf) {
#pragma unroll
            for (int reg = 0; reg < 4; ++reg) {
                const int pixg = pixg0 + nf * 16 + l15;
                const int b    = pixg >> 14;
                const int pix  = pixg & (HW_ - 1);
                const int oc   = mf * 16 + quad * 4 + reg;
                part[(size_t)ks * (B_ * C_ * HW_) +
                     ((size_t)(b * C_ + oc)) * HW_ + pix] = acc[mf][nf][reg];
            }
        }
    }
}

// ---------------------------------------------------------------------------
// Combine the 3 K-slice partials into d_out (float4 vectorized).
// ---------------------------------------------------------------------------
__global__ __launch_bounds__(256) void combine3_k(
    const float4* __restrict__ part, float4* __restrict__ out)
{
    constexpr int N4 = B_ * C_ * HW_ / 4;   // 524288
    const int i = blockIdx.x * 256 + threadIdx.x;
    if (i >= N4) return;
    float4 a = part[i];
    const float4 b = part[i + N4];
    const float4 c = part[i + 2 * N4];
    a.x += b.x + c.x;
    a.y += b.y + c.y;
    a.z += b.z + c.z;
    a.w += b.w + c.w;
    out[i] = a;
}

// ---------------------------------------------------------------------------
extern "C" void kernel_launch(void* const* d_in, const int* in_sizes, int n_in,
                              void* d_out, int out_size, void* d_ws, size_t ws_size,
                              hipStream_t stream)
{
    const float* x    = (const float*)d_in[0];
    const float* ef   = (const float*)d_in[1];
    const float* flow = (const float*)d_in[2];
    const float* w1   = (const float*)d_in[3];
    const float* b1   = (const float*)d_in[4];
    const float* w2   = (const float*)d_in[5];
    const float* b2   = (const float*)d_in[6];
    const float* w3   = (const float*)d_in[7];
    const float* b3   = (const float*)d_in[8];
    const float* wk   = (const float*)d_in[9];
    float* out = (float*)d_out;

    // Workspace (half slots unless noted):
    //   omh 14,155,776 | valh 18,874,368 | ef_s 4,194,304 | xn 2,097,152
    //   h1s 2,097,152 | h2s 2,097,152 | w1A 73,728 | w2A 36,864
    //   w3A 248,832 | wkA 36,864 | part 3*B*C*HW floats (optional, else alias omh)
    _Float16* omh  = (_Float16*)d_ws;
    _Float16* valh = omh + (size_t)B_ * OFFC_ * HW_;
    _Float16* ef_s = valh + (size_t)B_ * HW_ * R_;
    _Float16* xn   = ef_s + (size_t)4 * B_ * HW_ * 32;
    _Float16* h1s  = xn + (size_t)B_ * HW_ * 64;
    _Float16* h2s  = h1s + (size_t)2 * B_ * HW_ * 32;
    _Float16* w1A  = h2s + (size_t)2 * B_ * HW_ * 32;
    _Float16* w2A  = w1A + 64 * 128 * 9;
    _Float16* w3A  = w2A + 64 * 64 * 9;
    _Float16* wkA  = w3A + OFFC_ * 64 * 9;
    float*    end  = (float*)(wkA + 18 * 64 * 32);
    const size_t need_sep =
        ((char*)end - (char*)d_ws) + (size_t)3 * B_ * C_ * HW_ * 4;
    float*    part = (ws_size >= need_sep) ? end : (float*)omh;  // constant per deployment

    prep_wA_k<64, 128><<<dim3((64 * 128 * 9 + 255) / 256), 256, 0, stream>>>(w1, w1A);
    prep_wA_k<64, 64><<<dim3((64 * 64 * 9 + 255) / 256), 256, 0, stream>>>(w2, w2A);
    prep_wA_k<OFFC_, 64><<<dim3((OFFC_ * 64 * 9 + 255) / 256), 256, 0, stream>>>(w3, w3A);
    prep_wkA_k<<<dim3((18 * 64 * 32 + 255) / 256), 256, 0, stream>>>(wk, wkA);
    nchw2slab_f16_k<128><<<dim3(HW_ / 256, B_), 256, 0, stream>>>(ef, ef_s);
    nchw2nhwc_f16_k<64><<<dim3(HW_ / 256, B_), 256, 0, stream>>>(x, xn);

    conv12_mfma_k<128><<<dim3(B_ * H_ * 2, 4), 256, 0, stream>>>(ef_s, w1A, b1, h1s);
    conv12_mfma_k<64><<<dim3(B_ * H_ * 2, 4), 256, 0, stream>>>(h1s, w2A, b2, h2s);
    conv3_mfma_k<<<dim3(B_ * H_, 9), 256, 0, stream>>>(h2s, w3A, b3, flow, omh);

    gather_k<<<dim3(HW_ / 64, B_ * 4 * KK_), 256, 0, stream>>>(xn, omh, valh);
    einsum_mfma_k<<<dim3(B_ * HW_ / 128, 3), 256, 0, stream>>>(valh, wkA, part);
    combine3_k<<<dim3((B_ * C_ * HW_ / 4 + 255) / 256), 256, 0, stream>>>((const float4*)part, (float4*)out);
}